// Round 6
// baseline (993.599 us; speedup 1.0000x reference)
//
#include <hip/hip_runtime.h>

// HeteroGAT: 2-layer bipartite GAT (heads=4,ch=25 concat + edge feat; then heads=1,ch=100).
// R6: layer-1 gather HBM-bound -> packed bf16 src tables [N][104].
// R7: layer-2 src tables bf16 [N][100] (-27us; tables were cache-absorbed).
// R8: X staged via LDS (gemm 346 -> ~270us).
// R9: W staged via LDS too -> total 1213->991us. gemms off the top-5.
// R10 (resubmit; round 5 never acquired a GPU): gather4 (271us) is latency-bound,
//      NOT BW-bound: tables fit L3, VALUBusy 37%, two serialized random-load chains
//      per 2-edge iter (ss -> row -> asrc/values).
//   -> wave-register edge cache: per 64-edge chunk, ONE coalesced ss/sw load into
//      lanes + per-lane 4B gather of packed a_src; in-loop edge data via __shfl
//      (broadcast). Only 2 value loads/edge remain; addresses register-derived, so
//      4-edge groups issue 8 loads before compute. Same for gather1 (+ per-lane
//      pre-gather of fp32 as_ logits). Accumulation order verbatim -> bit-identical.

#define NNODES 50000
#define NEDGES 800000
#define SCAN_T 1024
#define SCAN_NBLK ((NNODES + SCAN_T - 1) / SCAN_T)  // 49

typedef unsigned short u16;
typedef unsigned int u32;

__device__ __forceinline__ float b2f(u16 u) {
    union { u32 i; float f; } x;
    x.i = ((u32)u) << 16;
    return x.f;
}
__device__ __forceinline__ u16 f2b(float f) {  // RN-even
    union { float f; u32 i; } x;
    x.f = f;
    u32 r = x.i + 0x7FFFu + ((x.i >> 16) & 1u);
    return (u16)(r >> 16);
}

// ---------------- ce[h] = sum_c We[h*25+c]*ae[h*25+c] (edge-attn constant) ----------------
__global__ void ce_kernel(const float* __restrict__ WeA, const float* __restrict__ aeA,
                          const float* __restrict__ WeB, const float* __restrict__ aeB,
                          float* __restrict__ ce /*[8]: 0..3=AB, 4..7=BA*/) {
    const float* We = blockIdx.x ? WeB : WeA;
    const float* ae = blockIdx.x ? aeB : aeA;
    __shared__ float s[4];
    int tid = threadIdx.x;
    if (tid < 4) s[tid] = 0.f;
    __syncthreads();
    if (tid < 100) atomicAdd(&s[tid / 25], We[tid] * ae[tid]);
    __syncthreads();
    if (tid < 4) ce[blockIdx.x * 4 + tid] = s[tid];
}

// ---------------- CSR build ----------------
__global__ void count_kernel(const int* __restrict__ eiA, const int* __restrict__ eiB,
                             int E, int* cntA, int* cntB) {
    int i = blockIdx.x * blockDim.x + threadIdx.x;
    if (i < E) atomicAdd(&cntA[eiA[E + i]], 1);
    else if (i < 2 * E) atomicAdd(&cntB[eiB[E + (i - E)]], 1);
}

__global__ __launch_bounds__(SCAN_T) void scanA_kernel(
    const int* __restrict__ cntA, const int* __restrict__ cntB,
    int* __restrict__ roA, int* __restrict__ roB, int* __restrict__ partial, int N) {
    const int dir = blockIdx.y;
    const int* cnt = dir ? cntB : cntA;
    int* ro = dir ? roB : roA;
    const int tid = threadIdx.x;
    const int i = blockIdx.x * SCAN_T + tid;
    __shared__ int sm[SCAN_T];
    sm[tid] = (i < N) ? cnt[i] : 0;
    __syncthreads();
    for (int off = 1; off < SCAN_T; off <<= 1) {
        int t = (tid >= off) ? sm[tid - off] : 0;
        __syncthreads();
        sm[tid] += t;
        __syncthreads();
    }
    if (i < N) ro[i + 1] = sm[tid];
    if (tid == SCAN_T - 1) partial[dir * 64 + blockIdx.x] = sm[tid];
}

__global__ void scanB_kernel(int* __restrict__ partial, int nblk) {
    __shared__ int sm[128];
    const int tid = threadIdx.x;
    sm[tid] = ((tid & 63) < nblk) ? partial[tid] : 0;
    __syncthreads();
    if (tid < 2) {
        int run = 0;
        for (int b = 0; b < nblk; ++b) {
            int t = sm[tid * 64 + b];
            sm[tid * 64 + b] = run;
            run += t;
        }
    }
    __syncthreads();
    partial[tid] = sm[tid];
}

__global__ __launch_bounds__(SCAN_T) void scanC_kernel(
    const int* __restrict__ cntA, const int* __restrict__ cntB,
    int* __restrict__ roA, int* __restrict__ roB,
    int* __restrict__ curA, int* __restrict__ curB,
    const int* __restrict__ partial, int N) {
    const int dir = blockIdx.y;
    const int* cnt = dir ? cntB : cntA;
    int* ro = dir ? roB : roA;
    int* cur = dir ? curB : curA;
    const int poff = partial[dir * 64 + blockIdx.x];
    const int i = blockIdx.x * SCAN_T + threadIdx.x;
    if (i < N) {
        int c = cnt[i];
        int r = ro[i + 1] + poff;
        ro[i + 1] = r;
        cur[i] = r - c;
        if (i == 0) ro[0] = 0;
    }
}

__global__ void fill_kernel(const int* __restrict__ eiA, const int* __restrict__ eiB,
                            const float* __restrict__ wA, const float* __restrict__ wB,
                            int E, int* curA, int* curB,
                            int* __restrict__ ssA, int* __restrict__ ssB,
                            float* __restrict__ swA, float* __restrict__ swB) {
    int i = blockIdx.x * blockDim.x + threadIdx.x;
    if (i < E) {
        int s = eiA[i], d = eiA[E + i];
        int pos = atomicAdd(&curA[d], 1);
        ssA[pos] = s; swA[pos] = wA[i];
    } else if (i < 2 * E) {
        int j = i - E;
        int s = eiB[j], d = eiB[E + j];
        int pos = atomicAdd(&curB[d], 1);
        ssB[pos] = s; swB[pos] = wB[j];
    }
}

// ---------------- GEMM [N,K]x[K,100] + fused att ----------------
// 128 nodes/block; lane owns nodes (lane, lane+64); wave w owns cols [25w,25w+25).
// R8/R9: BOTH operands staged via LDS per 32-wide K-chunk, double-buffered:
//   X [2][128][33] f32 (+1 pad, conflict-free per-lane reads)
//   W [2][4][32][28] f32 wave-sliced (16B-aligned 25-float slices, broadcast reads)
// Prefetch (global->reg) issued before compute; reg->LDS after; 1 barrier/chunk.
struct GemmArgs {
    const float* X;
    const float* W;
    const float* a;
    void* H;
    float* att;
};

template <int K, int HEADS>
__global__ __launch_bounds__(256, 2) void gemm_att_kernel(
    GemmArgs g0, GemmArgs g1, GemmArgs g2, GemmArgs g3, int N) {
    const GemmArgs ga[4] = {g0, g1, g2, g3};
    const GemmArgs g = ga[blockIdx.y];
    constexpr int XS_STRIDE = 33;
    constexpr int XS_BUF = 128 * XS_STRIDE;     // 4224 floats per buffer
    constexpr int WS_STRIDE = 28;               // 112B rows -> 16B aligned slices
    constexpr int WS_WAVE = 32 * WS_STRIDE;     // 896 floats per wave slice
    constexpr int WS_BUF = 4 * WS_WAVE;         // 3584 floats per buffer
    constexpr int SMEM_BYTES = (2 * XS_BUF + 2 * WS_BUF) * 4;  // 62464
    __shared__ __align__(16) char smem[SMEM_BYTES];
    const int tid = threadIdx.x;
    const int lane = tid & 63;
    const int w = tid >> 6;
    const int node0 = blockIdx.x * 128;
    const int nA = node0 + lane;
    const int nB = node0 + 64 + lane;
    const bool vA = nA < N, vB = nB < N;

    const int c0 = __builtin_amdgcn_readfirstlane(25 * w);  // wave-uniform

    float acc0[25], acc1[25];
#pragma unroll
    for (int j = 0; j < 25; ++j) { acc0[j] = 0.f; acc1[j] = 0.f; }

    float* Xs = (float*)smem;
    float* Wsh = (float*)smem + 2 * XS_BUF;
    float4 rv[4];
    float wv[13];

    // X tile load: slot s -> node n = s>>3, k-offset ko = (s&7)*4 (8 lanes per 128B line)
    auto issue_x = [&](int k0) {
#pragma unroll
        for (int r = 0; r < 4; ++r) {
            const int s = tid + r * 256;
            const int n = s >> 3;
            const int ko = (s & 7) * 4;
            int row = node0 + n;
            if (row >= N) row = N - 1;  // valid addr; values masked in epilogue
            const float* xp = g.X + (size_t)row * K + k0 + ko;
            if constexpr (K % 32 == 0) {
                rv[r] = *(const float4*)xp;
            } else {
                const int kb = k0 + ko;
                float4 v = make_float4(0.f, 0.f, 0.f, 0.f);
                if (kb + 3 < K) {
                    v = *(const float4*)xp;
                } else {
                    if (kb < K) v.x = xp[0];
                    if (kb + 1 < K) v.y = xp[1];
                    if (kb + 2 < K) v.z = xp[2];
                }
                rv[r] = v;
            }
        }
    };
    auto write_x = [&](int buf) {
#pragma unroll
        for (int r = 0; r < 4; ++r) {
            const int s = tid + r * 256;
            const int n = s >> 3;
            const int ko = (s & 7) * 4;
            float* dst = Xs + buf * XS_BUF + n * XS_STRIDE + ko;
            dst[0] = rv[r].x;
            dst[1] = rv[r].y;
            dst[2] = rv[r].z;
            dst[3] = rv[r].w;
        }
    };
    // W tile load: 32x100 rows (kc rows valid), contiguous global reads
    auto issue_w = [&](int k0, int kc) {
        const int lim = kc * 100;
#pragma unroll
        for (int r = 0; r < 13; ++r) {
            const int e = tid + r * 256;
            wv[r] = (e < lim) ? g.W[(size_t)k0 * 100 + e] : 0.f;
        }
    };
    auto write_w = [&](int buf, int kc) {
        const int lim = kc * 100;
#pragma unroll
        for (int r = 0; r < 13; ++r) {
            const int e = tid + r * 256;
            if (e < lim) {
                const int k = e / 100;
                const int j = e - k * 100;
                const int hd = j / 25;
                const int jj = j - hd * 25;
                Wsh[buf * WS_BUF + hd * WS_WAVE + k * WS_STRIDE + jj] = wv[r];
            }
        }
    };

    constexpr int C = (K + 31) / 32;
    {
        const int kc0 = (K < 32) ? K : 32;
        issue_x(0);
        issue_w(0, kc0);
        write_x(0);
        write_w(0, kc0);
    }
    __syncthreads();
    for (int c = 0; c < C; ++c) {
        const int k0 = c * 32;
        const int kc = (K - k0 < 32) ? (K - k0) : 32;
        const int kcn = (K - k0 - 32 < 32) ? (K - k0 - 32) : 32;
        if (c + 1 < C) {
            issue_x(k0 + 32);
            issue_w(k0 + 32, kcn);
        }
        const float* x0p = Xs + (c & 1) * XS_BUF + lane * XS_STRIDE;
        const float* x1p = x0p + 64 * XS_STRIDE;
        const float* wp = Wsh + (c & 1) * WS_BUF + w * WS_WAVE;
#pragma unroll 4
        for (int kk = 0; kk < kc; ++kk) {
            const float xs0 = x0p[kk];
            const float xs1 = x1p[kk];
            float wr[25];
#pragma unroll
            for (int j = 0; j < 25; ++j) wr[j] = wp[kk * WS_STRIDE + j];
#pragma unroll
            for (int j = 0; j < 25; ++j) {
                acc0[j] = fmaf(xs0, wr[j], acc0[j]);
                acc1[j] = fmaf(xs1, wr[j], acc1[j]);
            }
        }
        if (c + 1 < C) {
            __syncthreads();  // all waves done reading buf (c+1)&1 before overwrite
            write_x((c + 1) & 1);
            write_w((c + 1) & 1, kcn);
        }
        __syncthreads();
    }

    float ap0 = 0.f, ap1 = 0.f;
#pragma unroll
    for (int j = 0; j < 25; ++j) {
        const float av = g.a[c0 + j];
        ap0 = fmaf(acc0[j], av, ap0);
        ap1 = fmaf(acc1[j], av, ap1);
    }

    const int rem = N - node0;
    if (HEADS == 4) {
        if (g.H == nullptr) {  // dst role: a_dst only
            if (vA) g.att[(size_t)nA * 4 + w] = ap0;
            if (vB) g.att[(size_t)nB * 4 + w] = ap1;
        } else {               // src role: packed bf16 rows [104], LDS stride 106 (odd uints)
            u16* sh = (u16*)smem;
            u32* sh32 = (u32*)smem;
            // chunk A
#pragma unroll
            for (int j = 0; j < 25; ++j) sh[lane * 106 + c0 + j] = f2b(acc0[j]);
            sh[lane * 106 + 100 + w] = f2b(ap0);
            __syncthreads();
            {
                const int limA = ((rem < 64) ? rem : 64) * 52;
                u32* Hb = (u32*)g.H + (size_t)node0 * 52;
                for (int i = tid; i < 64 * 52; i += 256) {
                    if (i < limA) {
                        int nd = i / 52;
                        Hb[i] = sh32[nd * 53 + (i - nd * 52)];
                    }
                }
            }
            __syncthreads();
            // chunk B
#pragma unroll
            for (int j = 0; j < 25; ++j) sh[lane * 106 + c0 + j] = f2b(acc1[j]);
            sh[lane * 106 + 100 + w] = f2b(ap1);
            __syncthreads();
            {
                const int remB = rem - 64;
                const int limB = ((remB < 64) ? (remB < 0 ? 0 : remB) : 64) * 52;
                u32* Hb = (u32*)g.H + (size_t)(node0 + 64) * 52;
                for (int i = tid; i < 64 * 52; i += 256) {
                    if (i < limB) {
                        int nd = i / 52;
                        Hb[i] = sh32[nd * 53 + (i - nd * 52)];
                    }
                }
            }
        }
    } else {
        // HEADS==1: packed bf16 rows [100] (50 u32), LDS stride 102 u16 (51 u32, odd)
        u16* sh = (u16*)smem;
        u32* sh32 = (u32*)smem;
        float* attp = (float*)(smem + 64 * 102 * 2);
        attp[w * 128 + lane] = ap0;
        attp[w * 128 + 64 + lane] = ap1;
        if (g.H != nullptr) {
            // chunk A
#pragma unroll
            for (int j = 0; j < 25; ++j) sh[lane * 102 + c0 + j] = f2b(acc0[j]);
            __syncthreads();
            {
                const int limA = ((rem < 64) ? rem : 64) * 50;
                u32* Hb = (u32*)g.H + (size_t)node0 * 50;
                for (int i = tid; i < 64 * 50; i += 256) {
                    if (i < limA) {
                        int nd = i / 50;
                        Hb[i] = sh32[nd * 51 + (i - nd * 50)];
                    }
                }
                if (tid < 128 && node0 + tid < N)
                    g.att[node0 + tid] =
                        attp[tid] + attp[128 + tid] + attp[256 + tid] + attp[384 + tid];
            }
            __syncthreads();
            // chunk B
#pragma unroll
            for (int j = 0; j < 25; ++j) sh[lane * 102 + c0 + j] = f2b(acc1[j]);
            __syncthreads();
            {
                const int remB = rem - 64;
                const int limB = ((remB < 64) ? (remB < 0 ? 0 : remB) : 64) * 50;
                u32* Hb = (u32*)g.H + (size_t)(node0 + 64) * 50;
                for (int i = tid; i < 64 * 50; i += 256) {
                    if (i < limB) {
                        int nd = i / 50;
                        Hb[i] = sh32[nd * 51 + (i - nd * 50)];
                    }
                }
            }
        } else {
            __syncthreads();
            if (tid < 128 && node0 + tid < N)
                g.att[node0 + tid] =
                    attp[tid] + attp[128 + tid] + attp[256 + tid] + attp[384 + tid];
        }
    }
}

// ---------------- layer-1 gather: wave per dst node, packed bf16 src rows ----------------
// R10: 64-edge register cache (ss/sw/a_src preloaded into lanes, shfl-broadcast in loop);
// only 2 value loads per edge remain, addresses register-derived -> deep MLP.
struct Gather4Args {
    const int* ro;
    const int* ss;
    const float* sw;
    const u16* hp;     // [Ns][104] bf16: 0..99 h, 100..103 a_src
    const float* ad;   // [Nd,4] fp32
    const float* ce;   // [4]
    const float* bias; // [100]
    float* outp;       // [Nd,100]
};

__global__ __launch_bounds__(256) void gather4_kernel(Gather4Args ga0, Gather4Args ga1, int Nd) {
    const Gather4Args ga[2] = {ga0, ga1};
    const Gather4Args g = ga[blockIdx.y];
    int wid = (int)((blockIdx.x * blockDim.x + threadIdx.x) >> 6);
    if (wid >= Nd) return;
    const int n = __builtin_amdgcn_readfirstlane(wid);
    const int lane = threadIdx.x & 63;
    const int beg = g.ro[n], end = g.ro[n + 1];
    const int c0 = lane, c1 = 64 + lane;
    const bool has1 = (c1 < 100);
    const int h0 = c0 / 25;
    const int h1 = (c1 / 25) & 3;
    const float ce0 = g.ce[h0], ce1 = g.ce[h1];
    const float ad0 = g.ad[n * 4 + h0], ad1 = g.ad[n * 4 + h1];
    float acc0 = 0.f, acc1 = 0.f, d0 = 0.f, d1 = 0.f;

    struct EV { float v0, v1, l0, l1; };

    for (int base = beg; base < end; base += 64) {
        const int m = (end - base < 64) ? (end - base) : 64;
        const int li = (lane < m) ? lane : 0;
        const int ss_l = g.ss[base + li];
        const float sw_l = g.sw[base + li];
        const u16* rl = g.hp + (size_t)ss_l * 104;
        const u32 a01_l = *(const u32*)(rl + 100);  // a_src heads 0,1 (bf16x2)
        const u32 a23_l = *(const u32*)(rl + 102);  // a_src heads 2,3

        auto ld = [&](int q) -> EV {
            EV e;
            const int s_q = __shfl(ss_l, q);
            const u16* rq = g.hp + (size_t)s_q * 104;
            e.v0 = b2f(rq[c0]);
            e.v1 = has1 ? b2f(rq[c1]) : 0.f;
            const float wq = __shfl(sw_l, q);
            const u32 p01 = (u32)__shfl((int)a01_l, q);
            const u32 p23 = (u32)__shfl((int)a23_l, q);
            const u32 w0 = (h0 & 2) ? p23 : p01;
            const u32 w1 = (h1 & 2) ? p23 : p01;
            const float as0 = b2f((h0 & 1) ? (u16)(w0 >> 16) : (u16)w0);
            const float as1 = b2f((h1 & 1) ? (u16)(w1 >> 16) : (u16)w1);
            float l0 = as0 + ad0 + wq * ce0;
            float l1 = as1 + ad1 + wq * ce1;
            e.l0 = fmaxf(l0, 0.2f * l0);
            e.l1 = fmaxf(l1, 0.2f * l1);
            return e;
        };
        auto pairc = [&](const EV& A, const EV& B) {
            const float pa0 = __expf(A.l0), pa1 = __expf(A.l1);
            const float pb0 = __expf(B.l0), pb1 = __expf(B.l1);
            acc0 = fmaf(pa0, A.v0, acc0); acc0 = fmaf(pb0, B.v0, acc0);
            acc1 = fmaf(pa1, A.v1, acc1); acc1 = fmaf(pb1, B.v1, acc1);
            d0 += pa0 + pb0;
            d1 += pa1 + pb1;
        };

        int i = 0;
        for (; i + 3 < m; i += 4) {
            const EV e0 = ld(i), e1 = ld(i + 1), e2 = ld(i + 2), e3 = ld(i + 3);
            pairc(e0, e1);
            pairc(e2, e3);
        }
        for (; i + 1 < m; i += 2) {
            const EV e0 = ld(i), e1 = ld(i + 1);
            pairc(e0, e1);
        }
        if (i < m) {
            const EV e = ld(i);
            const float p0 = __expf(e.l0);
            const float p1 = __expf(e.l1);
            acc0 = fmaf(p0, e.v0, acc0);
            acc1 = fmaf(p1, e.v1, acc1);
            d0 += p0;
            d1 += p1;
        }
    }

    float r0 = (end > beg) ? acc0 / d0 : 0.f;
    float r1 = (end > beg) ? acc1 / d1 : 0.f;
    r0 += g.bias[c0];
    r0 = (r0 > 0.f) ? r0 : (__expf(r0) - 1.f);  // elu
    g.outp[(size_t)n * 100 + c0] = r0;
    if (has1) {
        r1 += g.bias[c1];
        r1 = (r1 > 0.f) ? r1 : (__expf(r1) - 1.f);
        g.outp[(size_t)n * 100 + c1] = r1;
    }
}

// ---------------- layer-2 gather: wave per dst node, heads=1, ch=100, bf16 rows ----------------
// R10: same 64-edge register cache; as_ logits pre-gathered per-lane (one gather
// replaces 16 per-edge scalar loads).
struct Gather1Args {
    const int* ro;
    const int* ss;
    const u16* hp;     // [Ns][100] bf16
    const float* as_;  // [Ns] fp32
    const float* ad;   // [Nd] fp32
    const float* bias; // [100]
    float* outp;       // [Nd,100]
};

__global__ __launch_bounds__(256) void gather1_kernel(Gather1Args ga0, Gather1Args ga1, int Nd) {
    const Gather1Args ga[2] = {ga0, ga1};
    const Gather1Args g = ga[blockIdx.y];
    int wid = (int)((blockIdx.x * blockDim.x + threadIdx.x) >> 6);
    if (wid >= Nd) return;
    const int n = __builtin_amdgcn_readfirstlane(wid);
    const int lane = threadIdx.x & 63;
    const int beg = g.ro[n], end = g.ro[n + 1];
    const int c0 = lane, c1 = 64 + lane;
    const bool has1 = (c1 < 100);
    const float adn = g.ad[n];
    float acc0 = 0.f, acc1 = 0.f, d0 = 0.f;

    struct EV1 { float v0, v1, l; };

    for (int base = beg; base < end; base += 64) {
        const int m = (end - base < 64) ? (end - base) : 64;
        const int li = (lane < m) ? lane : 0;
        const int ss_l = g.ss[base + li];
        const float as_l = g.as_[ss_l];  // per-lane gather of src logits

        auto ld = [&](int q) -> EV1 {
            EV1 e;
            const int s_q = __shfl(ss_l, q);
            const u16* rq = g.hp + (size_t)s_q * 100;
            e.v0 = b2f(rq[c0]);
            e.v1 = has1 ? b2f(rq[c1]) : 0.f;
            float l = __shfl(as_l, q) + adn;
            e.l = fmaxf(l, 0.2f * l);
            return e;
        };
        auto pairc = [&](const EV1& A, const EV1& B) {
            const float pa = __expf(A.l), pb = __expf(B.l);
            acc0 = fmaf(pa, A.v0, acc0); acc0 = fmaf(pb, B.v0, acc0);
            acc1 = fmaf(pa, A.v1, acc1); acc1 = fmaf(pb, B.v1, acc1);
            d0 += pa + pb;
        };

        int i = 0;
        for (; i + 3 < m; i += 4) {
            const EV1 e0 = ld(i), e1 = ld(i + 1), e2 = ld(i + 2), e3 = ld(i + 3);
            pairc(e0, e1);
            pairc(e2, e3);
        }
        for (; i + 1 < m; i += 2) {
            const EV1 e0 = ld(i), e1 = ld(i + 1);
            pairc(e0, e1);
        }
        if (i < m) {
            const EV1 e = ld(i);
            const float pe = __expf(e.l);
            acc0 = fmaf(pe, e.v0, acc0);
            acc1 = fmaf(pe, e.v1, acc1);
            d0 += pe;
        }
    }

    float r0 = (end > beg) ? acc0 / d0 : 0.f;
    float r1 = (end > beg) ? acc1 / d0 : 0.f;
    g.outp[(size_t)n * 100 + c0] = r0 + g.bias[c0];
    if (has1) g.outp[(size_t)n * 100 + c1] = r1 + g.bias[c1];
}

extern "C" void kernel_launch(void* const* d_in, const int* in_sizes, int n_in,
                              void* d_out, int out_size, void* d_ws, size_t ws_size,
                              hipStream_t stream) {
    const float* x_A   = (const float*)d_in[0];
    const float* x_B   = (const float*)d_in[1];
    const int*   ei_AB = (const int*)d_in[2];
    const int*   ei_BA = (const int*)d_in[3];
    const float* w_AB  = (const float*)d_in[4];
    const float* w_BA  = (const float*)d_in[5];
    const float* l1AB_Ws = (const float*)d_in[6];
    const float* l1AB_Wd = (const float*)d_in[7];
    const float* l1AB_as = (const float*)d_in[8];
    const float* l1AB_ad = (const float*)d_in[9];
    const float* l1AB_We = (const float*)d_in[10];
    const float* l1AB_ae = (const float*)d_in[11];
    const float* l1AB_b  = (const float*)d_in[12];
    const float* l2AB_Ws = (const float*)d_in[13];
    const float* l2AB_Wd = (const float*)d_in[14];
    const float* l2AB_as = (const float*)d_in[15];
    const float* l2AB_ad = (const float*)d_in[16];
    const float* l2AB_b  = (const float*)d_in[17];
    const float* l1BA_Ws = (const float*)d_in[18];
    const float* l1BA_Wd = (const float*)d_in[19];
    const float* l1BA_as = (const float*)d_in[20];
    const float* l1BA_ad = (const float*)d_in[21];
    const float* l1BA_We = (const float*)d_in[22];
    const float* l1BA_ae = (const float*)d_in[23];
    const float* l1BA_b  = (const float*)d_in[24];
    const float* l2BA_Ws = (const float*)d_in[25];
    const float* l2BA_Wd = (const float*)d_in[26];
    const float* l2BA_as = (const float*)d_in[27];
    const float* l2BA_ad = (const float*)d_in[28];
    const float* l2BA_b  = (const float*)d_in[29];

    const int N = NNODES, E = NEDGES;

    // ---- workspace carve (4-byte elements, 64-element aligned) ----
    size_t o = 0;
    auto alloc = [&](size_t n) { size_t r = o; o += (n + 63) & ~(size_t)63; return r; };
    size_t cntA = alloc(N), cntB = alloc(N);
    size_t roA = alloc(N + 1), roB = alloc(N + 1);
    size_t curA = alloc(N), curB = alloc(N);
    size_t ssA = alloc(E), ssB = alloc(E);
    size_t swA = alloc(E), swB = alloc(E);
    size_t ce8 = alloc(8);
    size_t part = alloc(128);
    size_t pHAB = alloc((size_t)N * 52);  // packed bf16 [N][104] as uints
    size_t pHBA = alloc((size_t)N * 52);
    size_t ad1B = alloc((size_t)N * 4), ad1A = alloc((size_t)N * 4);
    size_t hA1 = alloc((size_t)N * 100), hB1 = alloc((size_t)N * 100);
    size_t H2AB = alloc((size_t)N * 50);  // packed bf16 [N][100] as uints
    size_t H2BA = alloc((size_t)N * 50);
    size_t as2AB = alloc(N), as2BA = alloc(N);
    size_t ad2AB = alloc(N), ad2BA = alloc(N);
    (void)ws_size;

    float* wsf = (float*)d_ws;
    int*   wsi = (int*)d_ws;
    u32*   wsu = (u32*)d_ws;

    // zero edge-count histograms (cntA..cntB contiguous span)
    hipMemsetAsync(wsi + cntA, 0, sizeof(int) * (cntB + N - cntA), stream);

    ce_kernel<<<2, 128, 0, stream>>>(l1AB_We, l1AB_ae, l1BA_We, l1BA_ae, wsf + ce8);

    const int eb = (2 * E + 255) / 256;
    count_kernel<<<eb, 256, 0, stream>>>(ei_AB, ei_BA, E, wsi + cntA, wsi + cntB);
    scanA_kernel<<<dim3(SCAN_NBLK, 2), SCAN_T, 0, stream>>>(
        wsi + cntA, wsi + cntB, wsi + roA, wsi + roB, wsi + part, N);
    scanB_kernel<<<1, 128, 0, stream>>>(wsi + part, SCAN_NBLK);
    scanC_kernel<<<dim3(SCAN_NBLK, 2), SCAN_T, 0, stream>>>(
        wsi + cntA, wsi + cntB, wsi + roA, wsi + roB, wsi + curA, wsi + curB, wsi + part, N);
    fill_kernel<<<eb, 256, 0, stream>>>(ei_AB, ei_BA, w_AB, w_BA, E, wsi + curA, wsi + curB,
                                        wsi + ssA, wsi + ssB, wsf + swA, wsf + swB);

    const int gb = (N + 127) / 128;  // 391
    // layer-1 node transforms (src roles -> packed bf16 tables; dst roles -> a_dst only)
    {
        GemmArgs g0 = {x_A, l1AB_Ws, l1AB_as, (void*)(wsu + pHAB), nullptr};
        GemmArgs g1 = {x_B, l1AB_Wd, l1AB_ad, nullptr, wsf + ad1B};
        GemmArgs g2 = {x_B, l1BA_Ws, l1BA_as, (void*)(wsu + pHBA), nullptr};
        GemmArgs g3 = {x_A, l1BA_Wd, l1BA_ad, nullptr, wsf + ad1A};
        gemm_att_kernel<128, 4><<<dim3(gb, 4), 256, 0, stream>>>(g0, g1, g2, g3, N);
    }

    const int wb = (N + 3) / 4;  // wave per node, 4 waves/block
    {
        Gather4Args g0 = {wsi + roA, wsi + ssA, wsf + swA, (const u16*)(wsu + pHAB),
                          wsf + ad1B, wsf + ce8, l1AB_b, wsf + hB1};
        Gather4Args g1 = {wsi + roB, wsi + ssB, wsf + swB, (const u16*)(wsu + pHBA),
                          wsf + ad1A, wsf + ce8 + 4, l1BA_b, wsf + hA1};
        gather4_kernel<<<dim3(wb, 2), 256, 0, stream>>>(g0, g1, N);
    }

    // layer-2 node transforms (src roles -> packed bf16 H + as; dst roles -> ad only)
    {
        GemmArgs g0 = {wsf + hA1, l2AB_Ws, l2AB_as, (void*)(wsu + H2AB), wsf + as2AB};
        GemmArgs g1 = {wsf + hB1, l2AB_Wd, l2AB_ad, nullptr, wsf + ad2AB};
        GemmArgs g2 = {wsf + hB1, l2BA_Ws, l2BA_as, (void*)(wsu + H2BA), wsf + as2BA};
        GemmArgs g3 = {wsf + hA1, l2BA_Wd, l2BA_ad, nullptr, wsf + ad2BA};
        gemm_att_kernel<100, 1><<<dim3(gb, 4), 256, 0, stream>>>(g0, g1, g2, g3, N);
    }

    float* out = (float*)d_out;
    // oA = BA direction (dst in A) -> d_out[0..5M); oB = AB direction -> d_out[5M..10M)
    {
        Gather1Args g0 = {wsi + roA, wsi + ssA, (const u16*)(wsu + H2AB), wsf + as2AB,
                          wsf + ad2AB, l2AB_b, out + (size_t)N * 100};
        Gather1Args g1 = {wsi + roB, wsi + ssB, (const u16*)(wsu + H2BA), wsf + as2BA,
                          wsf + ad2BA, l2BA_b, out};
        gather1_kernel<<<dim3(wb, 2), 256, 0, stream>>>(g0, g1, N);
    }
}

// Round 7
// 980.223 us; speedup vs baseline: 1.0136x; 1.0136x over previous
//
#include <hip/hip_runtime.h>

// HeteroGAT: 2-layer bipartite GAT (heads=4,ch=25 concat + edge feat; then heads=1,ch=100).
// R6: layer-1 gather HBM-bound -> packed bf16 src tables [N][104].
// R7: layer-2 src tables bf16 [N][100] (-27us; cache-absorbed).
// R8/R9: gemm X+W staged via LDS -> total 1213->991us.
// R10: shfl edge-cache: FLAT (993us). Post-mortem: VGPR=28 -> compiler serialized the
//      "4-edge group" loads (no real MLP); a_src pre-gather added +100MB FETCH (row
//      sector re-fetch, working set > 4MB XCD-L2).
// R11: make MLP real: u32-packed values (lane<50 owns channels 2l,2l+1; 1 load/edge),
//      textually split load/compute phases with named scalars (8 independent loads per
//      4-edge group), a_src read per-edge from the value row's sector (no pre-gather).
//      gather1 same (keeps L2-resident as_ pre-gather). Bit-identical numerics.

#define NNODES 50000
#define NEDGES 800000
#define SCAN_T 1024
#define SCAN_NBLK ((NNODES + SCAN_T - 1) / SCAN_T)  // 49

typedef unsigned short u16;
typedef unsigned int u32;

__device__ __forceinline__ float b2f(u16 u) {
    union { u32 i; float f; } x;
    x.i = ((u32)u) << 16;
    return x.f;
}
__device__ __forceinline__ u16 f2b(float f) {  // RN-even
    union { float f; u32 i; } x;
    x.f = f;
    u32 r = x.i + 0x7FFFu + ((x.i >> 16) & 1u);
    return (u16)(r >> 16);
}

// ---------------- ce[h] = sum_c We[h*25+c]*ae[h*25+c] (edge-attn constant) ----------------
__global__ void ce_kernel(const float* __restrict__ WeA, const float* __restrict__ aeA,
                          const float* __restrict__ WeB, const float* __restrict__ aeB,
                          float* __restrict__ ce /*[8]: 0..3=AB, 4..7=BA*/) {
    const float* We = blockIdx.x ? WeB : WeA;
    const float* ae = blockIdx.x ? aeB : aeA;
    __shared__ float s[4];
    int tid = threadIdx.x;
    if (tid < 4) s[tid] = 0.f;
    __syncthreads();
    if (tid < 100) atomicAdd(&s[tid / 25], We[tid] * ae[tid]);
    __syncthreads();
    if (tid < 4) ce[blockIdx.x * 4 + tid] = s[tid];
}

// ---------------- CSR build ----------------
__global__ void count_kernel(const int* __restrict__ eiA, const int* __restrict__ eiB,
                             int E, int* cntA, int* cntB) {
    int i = blockIdx.x * blockDim.x + threadIdx.x;
    if (i < E) atomicAdd(&cntA[eiA[E + i]], 1);
    else if (i < 2 * E) atomicAdd(&cntB[eiB[E + (i - E)]], 1);
}

__global__ __launch_bounds__(SCAN_T) void scanA_kernel(
    const int* __restrict__ cntA, const int* __restrict__ cntB,
    int* __restrict__ roA, int* __restrict__ roB, int* __restrict__ partial, int N) {
    const int dir = blockIdx.y;
    const int* cnt = dir ? cntB : cntA;
    int* ro = dir ? roB : roA;
    const int tid = threadIdx.x;
    const int i = blockIdx.x * SCAN_T + tid;
    __shared__ int sm[SCAN_T];
    sm[tid] = (i < N) ? cnt[i] : 0;
    __syncthreads();
    for (int off = 1; off < SCAN_T; off <<= 1) {
        int t = (tid >= off) ? sm[tid - off] : 0;
        __syncthreads();
        sm[tid] += t;
        __syncthreads();
    }
    if (i < N) ro[i + 1] = sm[tid];
    if (tid == SCAN_T - 1) partial[dir * 64 + blockIdx.x] = sm[tid];
}

__global__ void scanB_kernel(int* __restrict__ partial, int nblk) {
    __shared__ int sm[128];
    const int tid = threadIdx.x;
    sm[tid] = ((tid & 63) < nblk) ? partial[tid] : 0;
    __syncthreads();
    if (tid < 2) {
        int run = 0;
        for (int b = 0; b < nblk; ++b) {
            int t = sm[tid * 64 + b];
            sm[tid * 64 + b] = run;
            run += t;
        }
    }
    __syncthreads();
    partial[tid] = sm[tid];
}

__global__ __launch_bounds__(SCAN_T) void scanC_kernel(
    const int* __restrict__ cntA, const int* __restrict__ cntB,
    int* __restrict__ roA, int* __restrict__ roB,
    int* __restrict__ curA, int* __restrict__ curB,
    const int* __restrict__ partial, int N) {
    const int dir = blockIdx.y;
    const int* cnt = dir ? cntB : cntA;
    int* ro = dir ? roB : roA;
    int* cur = dir ? curB : curA;
    const int poff = partial[dir * 64 + blockIdx.x];
    const int i = blockIdx.x * SCAN_T + threadIdx.x;
    if (i < N) {
        int c = cnt[i];
        int r = ro[i + 1] + poff;
        ro[i + 1] = r;
        cur[i] = r - c;
        if (i == 0) ro[0] = 0;
    }
}

__global__ void fill_kernel(const int* __restrict__ eiA, const int* __restrict__ eiB,
                            const float* __restrict__ wA, const float* __restrict__ wB,
                            int E, int* curA, int* curB,
                            int* __restrict__ ssA, int* __restrict__ ssB,
                            float* __restrict__ swA, float* __restrict__ swB) {
    int i = blockIdx.x * blockDim.x + threadIdx.x;
    if (i < E) {
        int s = eiA[i], d = eiA[E + i];
        int pos = atomicAdd(&curA[d], 1);
        ssA[pos] = s; swA[pos] = wA[i];
    } else if (i < 2 * E) {
        int j = i - E;
        int s = eiB[j], d = eiB[E + j];
        int pos = atomicAdd(&curB[d], 1);
        ssB[pos] = s; swB[pos] = wB[j];
    }
}

// ---------------- GEMM [N,K]x[K,100] + fused att ----------------
// 128 nodes/block; lane owns nodes (lane, lane+64); wave w owns cols [25w,25w+25).
// R8/R9: BOTH operands staged via LDS per 32-wide K-chunk, double-buffered.
struct GemmArgs {
    const float* X;
    const float* W;
    const float* a;
    void* H;
    float* att;
};

template <int K, int HEADS>
__global__ __launch_bounds__(256, 2) void gemm_att_kernel(
    GemmArgs g0, GemmArgs g1, GemmArgs g2, GemmArgs g3, int N) {
    const GemmArgs ga[4] = {g0, g1, g2, g3};
    const GemmArgs g = ga[blockIdx.y];
    constexpr int XS_STRIDE = 33;
    constexpr int XS_BUF = 128 * XS_STRIDE;     // 4224 floats per buffer
    constexpr int WS_STRIDE = 28;               // 112B rows -> 16B aligned slices
    constexpr int WS_WAVE = 32 * WS_STRIDE;     // 896 floats per wave slice
    constexpr int WS_BUF = 4 * WS_WAVE;         // 3584 floats per buffer
    constexpr int SMEM_BYTES = (2 * XS_BUF + 2 * WS_BUF) * 4;  // 62464
    __shared__ __align__(16) char smem[SMEM_BYTES];
    const int tid = threadIdx.x;
    const int lane = tid & 63;
    const int w = tid >> 6;
    const int node0 = blockIdx.x * 128;
    const int nA = node0 + lane;
    const int nB = node0 + 64 + lane;
    const bool vA = nA < N, vB = nB < N;

    const int c0 = __builtin_amdgcn_readfirstlane(25 * w);  // wave-uniform

    float acc0[25], acc1[25];
#pragma unroll
    for (int j = 0; j < 25; ++j) { acc0[j] = 0.f; acc1[j] = 0.f; }

    float* Xs = (float*)smem;
    float* Wsh = (float*)smem + 2 * XS_BUF;
    float4 rv[4];
    float wv[13];

    auto issue_x = [&](int k0) {
#pragma unroll
        for (int r = 0; r < 4; ++r) {
            const int s = tid + r * 256;
            const int n = s >> 3;
            const int ko = (s & 7) * 4;
            int row = node0 + n;
            if (row >= N) row = N - 1;  // valid addr; values masked in epilogue
            const float* xp = g.X + (size_t)row * K + k0 + ko;
            if constexpr (K % 32 == 0) {
                rv[r] = *(const float4*)xp;
            } else {
                const int kb = k0 + ko;
                float4 v = make_float4(0.f, 0.f, 0.f, 0.f);
                if (kb + 3 < K) {
                    v = *(const float4*)xp;
                } else {
                    if (kb < K) v.x = xp[0];
                    if (kb + 1 < K) v.y = xp[1];
                    if (kb + 2 < K) v.z = xp[2];
                }
                rv[r] = v;
            }
        }
    };
    auto write_x = [&](int buf) {
#pragma unroll
        for (int r = 0; r < 4; ++r) {
            const int s = tid + r * 256;
            const int n = s >> 3;
            const int ko = (s & 7) * 4;
            float* dst = Xs + buf * XS_BUF + n * XS_STRIDE + ko;
            dst[0] = rv[r].x;
            dst[1] = rv[r].y;
            dst[2] = rv[r].z;
            dst[3] = rv[r].w;
        }
    };
    auto issue_w = [&](int k0, int kc) {
        const int lim = kc * 100;
#pragma unroll
        for (int r = 0; r < 13; ++r) {
            const int e = tid + r * 256;
            wv[r] = (e < lim) ? g.W[(size_t)k0 * 100 + e] : 0.f;
        }
    };
    auto write_w = [&](int buf, int kc) {
        const int lim = kc * 100;
#pragma unroll
        for (int r = 0; r < 13; ++r) {
            const int e = tid + r * 256;
            if (e < lim) {
                const int k = e / 100;
                const int j = e - k * 100;
                const int hd = j / 25;
                const int jj = j - hd * 25;
                Wsh[buf * WS_BUF + hd * WS_WAVE + k * WS_STRIDE + jj] = wv[r];
            }
        }
    };

    constexpr int C = (K + 31) / 32;
    {
        const int kc0 = (K < 32) ? K : 32;
        issue_x(0);
        issue_w(0, kc0);
        write_x(0);
        write_w(0, kc0);
    }
    __syncthreads();
    for (int c = 0; c < C; ++c) {
        const int k0 = c * 32;
        const int kc = (K - k0 < 32) ? (K - k0) : 32;
        const int kcn = (K - k0 - 32 < 32) ? (K - k0 - 32) : 32;
        if (c + 1 < C) {
            issue_x(k0 + 32);
            issue_w(k0 + 32, kcn);
        }
        const float* x0p = Xs + (c & 1) * XS_BUF + lane * XS_STRIDE;
        const float* x1p = x0p + 64 * XS_STRIDE;
        const float* wp = Wsh + (c & 1) * WS_BUF + w * WS_WAVE;
#pragma unroll 4
        for (int kk = 0; kk < kc; ++kk) {
            const float xs0 = x0p[kk];
            const float xs1 = x1p[kk];
            float wr[25];
#pragma unroll
            for (int j = 0; j < 25; ++j) wr[j] = wp[kk * WS_STRIDE + j];
#pragma unroll
            for (int j = 0; j < 25; ++j) {
                acc0[j] = fmaf(xs0, wr[j], acc0[j]);
                acc1[j] = fmaf(xs1, wr[j], acc1[j]);
            }
        }
        if (c + 1 < C) {
            __syncthreads();  // all waves done reading buf (c+1)&1 before overwrite
            write_x((c + 1) & 1);
            write_w((c + 1) & 1, kcn);
        }
        __syncthreads();
    }

    float ap0 = 0.f, ap1 = 0.f;
#pragma unroll
    for (int j = 0; j < 25; ++j) {
        const float av = g.a[c0 + j];
        ap0 = fmaf(acc0[j], av, ap0);
        ap1 = fmaf(acc1[j], av, ap1);
    }

    const int rem = N - node0;
    if (HEADS == 4) {
        if (g.H == nullptr) {  // dst role: a_dst only
            if (vA) g.att[(size_t)nA * 4 + w] = ap0;
            if (vB) g.att[(size_t)nB * 4 + w] = ap1;
        } else {               // src role: packed bf16 rows [104], LDS stride 106 (odd uints)
            u16* sh = (u16*)smem;
            u32* sh32 = (u32*)smem;
            // chunk A
#pragma unroll
            for (int j = 0; j < 25; ++j) sh[lane * 106 + c0 + j] = f2b(acc0[j]);
            sh[lane * 106 + 100 + w] = f2b(ap0);
            __syncthreads();
            {
                const int limA = ((rem < 64) ? rem : 64) * 52;
                u32* Hb = (u32*)g.H + (size_t)node0 * 52;
                for (int i = tid; i < 64 * 52; i += 256) {
                    if (i < limA) {
                        int nd = i / 52;
                        Hb[i] = sh32[nd * 53 + (i - nd * 52)];
                    }
                }
            }
            __syncthreads();
            // chunk B
#pragma unroll
            for (int j = 0; j < 25; ++j) sh[lane * 106 + c0 + j] = f2b(acc1[j]);
            sh[lane * 106 + 100 + w] = f2b(ap1);
            __syncthreads();
            {
                const int remB = rem - 64;
                const int limB = ((remB < 64) ? (remB < 0 ? 0 : remB) : 64) * 52;
                u32* Hb = (u32*)g.H + (size_t)(node0 + 64) * 52;
                for (int i = tid; i < 64 * 52; i += 256) {
                    if (i < limB) {
                        int nd = i / 52;
                        Hb[i] = sh32[nd * 53 + (i - nd * 52)];
                    }
                }
            }
        }
    } else {
        // HEADS==1: packed bf16 rows [100] (50 u32), LDS stride 102 u16 (51 u32, odd)
        u16* sh = (u16*)smem;
        u32* sh32 = (u32*)smem;
        float* attp = (float*)(smem + 64 * 102 * 2);
        attp[w * 128 + lane] = ap0;
        attp[w * 128 + 64 + lane] = ap1;
        if (g.H != nullptr) {
            // chunk A
#pragma unroll
            for (int j = 0; j < 25; ++j) sh[lane * 102 + c0 + j] = f2b(acc0[j]);
            __syncthreads();
            {
                const int limA = ((rem < 64) ? rem : 64) * 50;
                u32* Hb = (u32*)g.H + (size_t)node0 * 50;
                for (int i = tid; i < 64 * 50; i += 256) {
                    if (i < limA) {
                        int nd = i / 50;
                        Hb[i] = sh32[nd * 51 + (i - nd * 50)];
                    }
                }
                if (tid < 128 && node0 + tid < N)
                    g.att[node0 + tid] =
                        attp[tid] + attp[128 + tid] + attp[256 + tid] + attp[384 + tid];
            }
            __syncthreads();
            // chunk B
#pragma unroll
            for (int j = 0; j < 25; ++j) sh[lane * 102 + c0 + j] = f2b(acc1[j]);
            __syncthreads();
            {
                const int remB = rem - 64;
                const int limB = ((remB < 64) ? (remB < 0 ? 0 : remB) : 64) * 50;
                u32* Hb = (u32*)g.H + (size_t)(node0 + 64) * 50;
                for (int i = tid; i < 64 * 50; i += 256) {
                    if (i < limB) {
                        int nd = i / 50;
                        Hb[i] = sh32[nd * 51 + (i - nd * 50)];
                    }
                }
            }
        } else {
            __syncthreads();
            if (tid < 128 && node0 + tid < N)
                g.att[node0 + tid] =
                    attp[tid] + attp[128 + tid] + attp[256 + tid] + attp[384 + tid];
        }
    }
}

// ---------------- layer-1 gather: wave per dst node, packed bf16 src rows ----------------
// R11: lane<50 owns channels (2l,2l+1); per edge ONE u32 value load + ONE u32 a_src load
// (same row sector). 4-edge groups: all 8 loads issued before compute (named scalars).
struct Gather4Args {
    const int* ro;
    const int* ss;
    const float* sw;
    const u16* hp;     // [Ns][104] bf16: 0..99 h, 100..103 a_src
    const float* ad;   // [Nd,4] fp32
    const float* ce;   // [4]
    const float* bias; // [100]
    float* outp;       // [Nd,100]
};

__global__ __launch_bounds__(256) void gather4_kernel(Gather4Args ga0, Gather4Args ga1, int Nd) {
    const Gather4Args ga[2] = {ga0, ga1};
    const Gather4Args g = ga[blockIdx.y];
    int wid = (int)((blockIdx.x * blockDim.x + threadIdx.x) >> 6);
    if (wid >= Nd) return;
    const int n = __builtin_amdgcn_readfirstlane(wid);
    const int lane = threadIdx.x & 63;
    const int beg = g.ro[n], end = g.ro[n + 1];
    const bool act = (lane < 50);
    const int cc0 = act ? 2 * lane : 0;   // channels (cc0, cc0+1)
    const int h0 = cc0 / 25;
    const int h1 = (cc0 + 1) / 25;        // == h0 or h0+1 (h0 even at boundaries)
    const int aoff = 2 * (h0 >> 1);       // u16 offset 100+aoff holds heads (h0&~1, h0&~1 +1)
    const float ce0 = g.ce[h0], ce1 = g.ce[h1];
    const float ad0 = g.ad[n * 4 + h0], ad1 = g.ad[n * 4 + h1];
    float acc0 = 0.f, acc1 = 0.f, d0 = 0.f, d1 = 0.f;

    for (int base = beg; base < end; base += 64) {
        const int m = (end - base < 64) ? (end - base) : 64;
        const int li = (lane < m) ? lane : 0;
        const int ss_l = g.ss[base + li];
        const float sw_l = g.sw[base + li];

        // per-edge compute from preloaded regs (values va/aa, weight wq)
        auto edge = [&](u32 va, u32 aa, float wq, float& p0o, float& p1o) {
            const float as0 = b2f((h0 & 1) ? (u16)(aa >> 16) : (u16)aa);
            const float as1 = b2f((h1 & 1) ? (u16)(aa >> 16) : (u16)aa);
            float l0 = as0 + ad0 + wq * ce0;
            float l1 = as1 + ad1 + wq * ce1;
            l0 = fmaxf(l0, 0.2f * l0);
            l1 = fmaxf(l1, 0.2f * l1);
            const float p0 = __expf(l0);
            const float p1 = __expf(l1);
            acc0 = fmaf(p0, b2f((u16)va), acc0);
            acc1 = fmaf(p1, b2f((u16)(va >> 16)), acc1);
            p0o = p0;
            p1o = p1;
        };

        int i = 0;
        for (; i + 3 < m; i += 4) {
            // ---- load phase: 8 independent loads ----
            const int s0 = __shfl(ss_l, i);
            const int s1 = __shfl(ss_l, i + 1);
            const int s2 = __shfl(ss_l, i + 2);
            const int s3 = __shfl(ss_l, i + 3);
            const float w0 = __shfl(sw_l, i);
            const float w1 = __shfl(sw_l, i + 1);
            const float w2 = __shfl(sw_l, i + 2);
            const float w3 = __shfl(sw_l, i + 3);
            const u16* r0 = g.hp + (size_t)s0 * 104;
            const u16* r1 = g.hp + (size_t)s1 * 104;
            const u16* r2 = g.hp + (size_t)s2 * 104;
            const u16* r3 = g.hp + (size_t)s3 * 104;
            const u32 va0 = *(const u32*)(r0 + cc0);
            const u32 va1 = *(const u32*)(r1 + cc0);
            const u32 va2 = *(const u32*)(r2 + cc0);
            const u32 va3 = *(const u32*)(r3 + cc0);
            const u32 aa0 = *(const u32*)(r0 + 100 + aoff);
            const u32 aa1 = *(const u32*)(r1 + 100 + aoff);
            const u32 aa2 = *(const u32*)(r2 + 100 + aoff);
            const u32 aa3 = *(const u32*)(r3 + 100 + aoff);
            // ---- compute phase ----
            float pa0, pa1, pb0, pb1;
            edge(va0, aa0, w0, pa0, pa1);
            edge(va1, aa1, w1, pb0, pb1);
            d0 += pa0 + pb0;
            d1 += pa1 + pb1;
            edge(va2, aa2, w2, pa0, pa1);
            edge(va3, aa3, w3, pb0, pb1);
            d0 += pa0 + pb0;
            d1 += pa1 + pb1;
        }
        for (; i + 1 < m; i += 2) {
            const int s0 = __shfl(ss_l, i);
            const int s1 = __shfl(ss_l, i + 1);
            const float w0 = __shfl(sw_l, i);
            const float w1 = __shfl(sw_l, i + 1);
            const u16* r0 = g.hp + (size_t)s0 * 104;
            const u16* r1 = g.hp + (size_t)s1 * 104;
            const u32 va0 = *(const u32*)(r0 + cc0);
            const u32 va1 = *(const u32*)(r1 + cc0);
            const u32 aa0 = *(const u32*)(r0 + 100 + aoff);
            const u32 aa1 = *(const u32*)(r1 + 100 + aoff);
            float pa0, pa1, pb0, pb1;
            edge(va0, aa0, w0, pa0, pa1);
            edge(va1, aa1, w1, pb0, pb1);
            d0 += pa0 + pb0;
            d1 += pa1 + pb1;
        }
        if (i < m) {
            const int s0 = __shfl(ss_l, i);
            const float w0 = __shfl(sw_l, i);
            const u16* r0 = g.hp + (size_t)s0 * 104;
            const u32 va0 = *(const u32*)(r0 + cc0);
            const u32 aa0 = *(const u32*)(r0 + 100 + aoff);
            float pa0, pa1;
            edge(va0, aa0, w0, pa0, pa1);
            d0 += pa0;
            d1 += pa1;
        }
    }

    if (act) {
        float r0 = (end > beg) ? acc0 / d0 : 0.f;
        float r1 = (end > beg) ? acc1 / d1 : 0.f;
        r0 += g.bias[cc0];
        r0 = (r0 > 0.f) ? r0 : (__expf(r0) - 1.f);  // elu
        r1 += g.bias[cc0 + 1];
        r1 = (r1 > 0.f) ? r1 : (__expf(r1) - 1.f);
        *(float2*)(g.outp + (size_t)n * 100 + cc0) = make_float2(r0, r1);
    }
}

// ---------------- layer-2 gather: wave per dst node, heads=1, ch=100, bf16 rows ----------------
// R11: lane<50 owns channels (2l,2l+1); one u32 value load/edge; as_ pre-gather kept
// (200KB table, L2-resident).
struct Gather1Args {
    const int* ro;
    const int* ss;
    const u16* hp;     // [Ns][100] bf16
    const float* as_;  // [Ns] fp32
    const float* ad;   // [Nd] fp32
    const float* bias; // [100]
    float* outp;       // [Nd,100]
};

__global__ __launch_bounds__(256) void gather1_kernel(Gather1Args ga0, Gather1Args ga1, int Nd) {
    const Gather1Args ga[2] = {ga0, ga1};
    const Gather1Args g = ga[blockIdx.y];
    int wid = (int)((blockIdx.x * blockDim.x + threadIdx.x) >> 6);
    if (wid >= Nd) return;
    const int n = __builtin_amdgcn_readfirstlane(wid);
    const int lane = threadIdx.x & 63;
    const int beg = g.ro[n], end = g.ro[n + 1];
    const bool act = (lane < 50);
    const int cc0 = act ? 2 * lane : 0;
    const float adn = g.ad[n];
    float acc0 = 0.f, acc1 = 0.f, d0 = 0.f;

    for (int base = beg; base < end; base += 64) {
        const int m = (end - base < 64) ? (end - base) : 64;
        const int li = (lane < m) ? lane : 0;
        const int ss_l = g.ss[base + li];
        const float as_l = g.as_[ss_l];  // per-lane gather of src logits (L2-resident)

        auto edge = [&](u32 va, float asq, float& po) {
            float l = asq + adn;
            l = fmaxf(l, 0.2f * l);
            const float p = __expf(l);
            acc0 = fmaf(p, b2f((u16)va), acc0);
            acc1 = fmaf(p, b2f((u16)(va >> 16)), acc1);
            po = p;
        };

        int i = 0;
        for (; i + 3 < m; i += 4) {
            const int s0 = __shfl(ss_l, i);
            const int s1 = __shfl(ss_l, i + 1);
            const int s2 = __shfl(ss_l, i + 2);
            const int s3 = __shfl(ss_l, i + 3);
            const float a0 = __shfl(as_l, i);
            const float a1 = __shfl(as_l, i + 1);
            const float a2 = __shfl(as_l, i + 2);
            const float a3 = __shfl(as_l, i + 3);
            const u32 va0 = *(const u32*)(g.hp + (size_t)s0 * 100 + cc0);
            const u32 va1 = *(const u32*)(g.hp + (size_t)s1 * 100 + cc0);
            const u32 va2 = *(const u32*)(g.hp + (size_t)s2 * 100 + cc0);
            const u32 va3 = *(const u32*)(g.hp + (size_t)s3 * 100 + cc0);
            float pa, pb;
            edge(va0, a0, pa);
            edge(va1, a1, pb);
            d0 += pa + pb;
            edge(va2, a2, pa);
            edge(va3, a3, pb);
            d0 += pa + pb;
        }
        for (; i + 1 < m; i += 2) {
            const int s0 = __shfl(ss_l, i);
            const int s1 = __shfl(ss_l, i + 1);
            const float a0 = __shfl(as_l, i);
            const float a1 = __shfl(as_l, i + 1);
            const u32 va0 = *(const u32*)(g.hp + (size_t)s0 * 100 + cc0);
            const u32 va1 = *(const u32*)(g.hp + (size_t)s1 * 100 + cc0);
            float pa, pb;
            edge(va0, a0, pa);
            edge(va1, a1, pb);
            d0 += pa + pb;
        }
        if (i < m) {
            const int s0 = __shfl(ss_l, i);
            const float a0 = __shfl(as_l, i);
            const u32 va0 = *(const u32*)(g.hp + (size_t)s0 * 100 + cc0);
            float pa;
            edge(va0, a0, pa);
            d0 += pa;
        }
    }

    if (act) {
        float r0 = (end > beg) ? acc0 / d0 : 0.f;
        float r1 = (end > beg) ? acc1 / d0 : 0.f;
        r0 += g.bias[cc0];
        r1 += g.bias[cc0 + 1];
        *(float2*)(g.outp + (size_t)n * 100 + cc0) = make_float2(r0, r1);
    }
}

extern "C" void kernel_launch(void* const* d_in, const int* in_sizes, int n_in,
                              void* d_out, int out_size, void* d_ws, size_t ws_size,
                              hipStream_t stream) {
    const float* x_A   = (const float*)d_in[0];
    const float* x_B   = (const float*)d_in[1];
    const int*   ei_AB = (const int*)d_in[2];
    const int*   ei_BA = (const int*)d_in[3];
    const float* w_AB  = (const float*)d_in[4];
    const float* w_BA  = (const float*)d_in[5];
    const float* l1AB_Ws = (const float*)d_in[6];
    const float* l1AB_Wd = (const float*)d_in[7];
    const float* l1AB_as = (const float*)d_in[8];
    const float* l1AB_ad = (const float*)d_in[9];
    const float* l1AB_We = (const float*)d_in[10];
    const float* l1AB_ae = (const float*)d_in[11];
    const float* l1AB_b  = (const float*)d_in[12];
    const float* l2AB_Ws = (const float*)d_in[13];
    const float* l2AB_Wd = (const float*)d_in[14];
    const float* l2AB_as = (const float*)d_in[15];
    const float* l2AB_ad = (const float*)d_in[16];
    const float* l2AB_b  = (const float*)d_in[17];
    const float* l1BA_Ws = (const float*)d_in[18];
    const float* l1BA_Wd = (const float*)d_in[19];
    const float* l1BA_as = (const float*)d_in[20];
    const float* l1BA_ad = (const float*)d_in[21];
    const float* l1BA_We = (const float*)d_in[22];
    const float* l1BA_ae = (const float*)d_in[23];
    const float* l1BA_b  = (const float*)d_in[24];
    const float* l2BA_Ws = (const float*)d_in[25];
    const float* l2BA_Wd = (const float*)d_in[26];
    const float* l2BA_as = (const float*)d_in[27];
    const float* l2BA_ad = (const float*)d_in[28];
    const float* l2BA_b  = (const float*)d_in[29];

    const int N = NNODES, E = NEDGES;

    // ---- workspace carve (4-byte elements, 64-element aligned) ----
    size_t o = 0;
    auto alloc = [&](size_t n) { size_t r = o; o += (n + 63) & ~(size_t)63; return r; };
    size_t cntA = alloc(N), cntB = alloc(N);
    size_t roA = alloc(N + 1), roB = alloc(N + 1);
    size_t curA = alloc(N), curB = alloc(N);
    size_t ssA = alloc(E), ssB = alloc(E);
    size_t swA = alloc(E), swB = alloc(E);
    size_t ce8 = alloc(8);
    size_t part = alloc(128);
    size_t pHAB = alloc((size_t)N * 52);  // packed bf16 [N][104] as uints
    size_t pHBA = alloc((size_t)N * 52);
    size_t ad1B = alloc((size_t)N * 4), ad1A = alloc((size_t)N * 4);
    size_t hA1 = alloc((size_t)N * 100), hB1 = alloc((size_t)N * 100);
    size_t H2AB = alloc((size_t)N * 50);  // packed bf16 [N][100] as uints
    size_t H2BA = alloc((size_t)N * 50);
    size_t as2AB = alloc(N), as2BA = alloc(N);
    size_t ad2AB = alloc(N), ad2BA = alloc(N);
    (void)ws_size;

    float* wsf = (float*)d_ws;
    int*   wsi = (int*)d_ws;
    u32*   wsu = (u32*)d_ws;

    // zero edge-count histograms (cntA..cntB contiguous span)
    hipMemsetAsync(wsi + cntA, 0, sizeof(int) * (cntB + N - cntA), stream);

    ce_kernel<<<2, 128, 0, stream>>>(l1AB_We, l1AB_ae, l1BA_We, l1BA_ae, wsf + ce8);

    const int eb = (2 * E + 255) / 256;
    count_kernel<<<eb, 256, 0, stream>>>(ei_AB, ei_BA, E, wsi + cntA, wsi + cntB);
    scanA_kernel<<<dim3(SCAN_NBLK, 2), SCAN_T, 0, stream>>>(
        wsi + cntA, wsi + cntB, wsi + roA, wsi + roB, wsi + part, N);
    scanB_kernel<<<1, 128, 0, stream>>>(wsi + part, SCAN_NBLK);
    scanC_kernel<<<dim3(SCAN_NBLK, 2), SCAN_T, 0, stream>>>(
        wsi + cntA, wsi + cntB, wsi + roA, wsi + roB, wsi + curA, wsi + curB, wsi + part, N);
    fill_kernel<<<eb, 256, 0, stream>>>(ei_AB, ei_BA, w_AB, w_BA, E, wsi + curA, wsi + curB,
                                        wsi + ssA, wsi + ssB, wsf + swA, wsf + swB);

    const int gb = (N + 127) / 128;  // 391
    // layer-1 node transforms (src roles -> packed bf16 tables; dst roles -> a_dst only)
    {
        GemmArgs g0 = {x_A, l1AB_Ws, l1AB_as, (void*)(wsu + pHAB), nullptr};
        GemmArgs g1 = {x_B, l1AB_Wd, l1AB_ad, nullptr, wsf + ad1B};
        GemmArgs g2 = {x_B, l1BA_Ws, l1BA_as, (void*)(wsu + pHBA), nullptr};
        GemmArgs g3 = {x_A, l1BA_Wd, l1BA_ad, nullptr, wsf + ad1A};
        gemm_att_kernel<128, 4><<<dim3(gb, 4), 256, 0, stream>>>(g0, g1, g2, g3, N);
    }

    const int wb = (N + 3) / 4;  // wave per node, 4 waves/block
    {
        Gather4Args g0 = {wsi + roA, wsi + ssA, wsf + swA, (const u16*)(wsu + pHAB),
                          wsf + ad1B, wsf + ce8, l1AB_b, wsf + hB1};
        Gather4Args g1 = {wsi + roB, wsi + ssB, wsf + swB, (const u16*)(wsu + pHBA),
                          wsf + ad1A, wsf + ce8 + 4, l1BA_b, wsf + hA1};
        gather4_kernel<<<dim3(wb, 2), 256, 0, stream>>>(g0, g1, N);
    }

    // layer-2 node transforms (src roles -> packed bf16 H + as; dst roles -> ad only)
    {
        GemmArgs g0 = {wsf + hA1, l2AB_Ws, l2AB_as, (void*)(wsu + H2AB), wsf + as2AB};
        GemmArgs g1 = {wsf + hB1, l2AB_Wd, l2AB_ad, nullptr, wsf + ad2AB};
        GemmArgs g2 = {wsf + hB1, l2BA_Ws, l2BA_as, (void*)(wsu + H2BA), wsf + as2BA};
        GemmArgs g3 = {wsf + hA1, l2BA_Wd, l2BA_ad, nullptr, wsf + ad2BA};
        gemm_att_kernel<100, 1><<<dim3(gb, 4), 256, 0, stream>>>(g0, g1, g2, g3, N);
    }

    float* out = (float*)d_out;
    // oA = BA direction (dst in A) -> d_out[0..5M); oB = AB direction -> d_out[5M..10M)
    {
        Gather1Args g0 = {wsi + roA, wsi + ssA, (const u16*)(wsu + H2AB), wsf + as2AB,
                          wsf + ad2AB, l2AB_b, out + (size_t)N * 100};
        Gather1Args g1 = {wsi + roB, wsi + ssB, (const u16*)(wsu + H2BA), wsf + as2BA,
                          wsf + ad2BA, l2BA_b, out};
        gather1_kernel<<<dim3(wb, 2), 256, 0, stream>>>(g0, g1, N);
    }
}

// Round 8
// 951.614 us; speedup vs baseline: 1.0441x; 1.0301x over previous
//
#include <hip/hip_runtime.h>

// HeteroGAT: 2-layer bipartite GAT (heads=4,ch=25 concat + edge feat; then heads=1,ch=100).
// R6: layer-1 gather HBM-bound -> packed bf16 src tables [N][104].
// R7: layer-2 src tables bf16 [N][100] (-27us; cache-absorbed).
// R8/R9: gemm X+W staged via LDS -> total 1213->991us.
// R10/R11: shfl edge-cache + named-scalar groups: nearly flat (993->980). Post-mortem:
//      VGPR=32 -> scheduler sinks loads to right-before-use; ~2300 cyc/edge serial chain;
//      66 VALU/edge (bpermute + per-lane addr math).
// R12: force the pipeline structurally:
//      (a) scalar SMEM edge loads: ss/sw via readfirstlane'd offsets -> s_load; scalar
//          row base; value/a_src are saddr loads with constant per-lane voffset.
//          Removes all per-edge bpermutes + address VALU.
//      (b) explicit 1-deep software pipeline over 4-edge groups with named double-buffer
//          structs + sched_barrier(0) between load-issue and compute (stops sinking).
//      (c) gather1 same; a_src scalar load replaces pre-gather+shfl.
//      Edge order / pairing / fma sequence verbatim -> bit-identical (absmax 0.00390625).

#define NNODES 50000
#define NEDGES 800000
#define SCAN_T 1024
#define SCAN_NBLK ((NNODES + SCAN_T - 1) / SCAN_T)  // 49

typedef unsigned short u16;
typedef unsigned int u32;

__device__ __forceinline__ float b2f(u16 u) {
    union { u32 i; float f; } x;
    x.i = ((u32)u) << 16;
    return x.f;
}
__device__ __forceinline__ u16 f2b(float f) {  // RN-even
    union { float f; u32 i; } x;
    x.f = f;
    u32 r = x.i + 0x7FFFu + ((x.i >> 16) & 1u);
    return (u16)(r >> 16);
}

// ---------------- ce[h] = sum_c We[h*25+c]*ae[h*25+c] (edge-attn constant) ----------------
__global__ void ce_kernel(const float* __restrict__ WeA, const float* __restrict__ aeA,
                          const float* __restrict__ WeB, const float* __restrict__ aeB,
                          float* __restrict__ ce /*[8]: 0..3=AB, 4..7=BA*/) {
    const float* We = blockIdx.x ? WeB : WeA;
    const float* ae = blockIdx.x ? aeB : aeA;
    __shared__ float s[4];
    int tid = threadIdx.x;
    if (tid < 4) s[tid] = 0.f;
    __syncthreads();
    if (tid < 100) atomicAdd(&s[tid / 25], We[tid] * ae[tid]);
    __syncthreads();
    if (tid < 4) ce[blockIdx.x * 4 + tid] = s[tid];
}

// ---------------- CSR build ----------------
__global__ void count_kernel(const int* __restrict__ eiA, const int* __restrict__ eiB,
                             int E, int* cntA, int* cntB) {
    int i = blockIdx.x * blockDim.x + threadIdx.x;
    if (i < E) atomicAdd(&cntA[eiA[E + i]], 1);
    else if (i < 2 * E) atomicAdd(&cntB[eiB[E + (i - E)]], 1);
}

__global__ __launch_bounds__(SCAN_T) void scanA_kernel(
    const int* __restrict__ cntA, const int* __restrict__ cntB,
    int* __restrict__ roA, int* __restrict__ roB, int* __restrict__ partial, int N) {
    const int dir = blockIdx.y;
    const int* cnt = dir ? cntB : cntA;
    int* ro = dir ? roB : roA;
    const int tid = threadIdx.x;
    const int i = blockIdx.x * SCAN_T + tid;
    __shared__ int sm[SCAN_T];
    sm[tid] = (i < N) ? cnt[i] : 0;
    __syncthreads();
    for (int off = 1; off < SCAN_T; off <<= 1) {
        int t = (tid >= off) ? sm[tid - off] : 0;
        __syncthreads();
        sm[tid] += t;
        __syncthreads();
    }
    if (i < N) ro[i + 1] = sm[tid];
    if (tid == SCAN_T - 1) partial[dir * 64 + blockIdx.x] = sm[tid];
}

__global__ void scanB_kernel(int* __restrict__ partial, int nblk) {
    __shared__ int sm[128];
    const int tid = threadIdx.x;
    sm[tid] = ((tid & 63) < nblk) ? partial[tid] : 0;
    __syncthreads();
    if (tid < 2) {
        int run = 0;
        for (int b = 0; b < nblk; ++b) {
            int t = sm[tid * 64 + b];
            sm[tid * 64 + b] = run;
            run += t;
        }
    }
    __syncthreads();
    partial[tid] = sm[tid];
}

__global__ __launch_bounds__(SCAN_T) void scanC_kernel(
    const int* __restrict__ cntA, const int* __restrict__ cntB,
    int* __restrict__ roA, int* __restrict__ roB,
    int* __restrict__ curA, int* __restrict__ curB,
    const int* __restrict__ partial, int N) {
    const int dir = blockIdx.y;
    const int* cnt = dir ? cntB : cntA;
    int* ro = dir ? roB : roA;
    int* cur = dir ? curB : curA;
    const int poff = partial[dir * 64 + blockIdx.x];
    const int i = blockIdx.x * SCAN_T + threadIdx.x;
    if (i < N) {
        int c = cnt[i];
        int r = ro[i + 1] + poff;
        ro[i + 1] = r;
        cur[i] = r - c;
        if (i == 0) ro[0] = 0;
    }
}

__global__ void fill_kernel(const int* __restrict__ eiA, const int* __restrict__ eiB,
                            const float* __restrict__ wA, const float* __restrict__ wB,
                            int E, int* curA, int* curB,
                            int* __restrict__ ssA, int* __restrict__ ssB,
                            float* __restrict__ swA, float* __restrict__ swB) {
    int i = blockIdx.x * blockDim.x + threadIdx.x;
    if (i < E) {
        int s = eiA[i], d = eiA[E + i];
        int pos = atomicAdd(&curA[d], 1);
        ssA[pos] = s; swA[pos] = wA[i];
    } else if (i < 2 * E) {
        int j = i - E;
        int s = eiB[j], d = eiB[E + j];
        int pos = atomicAdd(&curB[d], 1);
        ssB[pos] = s; swB[pos] = wB[j];
    }
}

// ---------------- GEMM [N,K]x[K,100] + fused att ----------------
// 128 nodes/block; lane owns nodes (lane, lane+64); wave w owns cols [25w,25w+25).
// R8/R9: BOTH operands staged via LDS per 32-wide K-chunk, double-buffered.
struct GemmArgs {
    const float* X;
    const float* W;
    const float* a;
    void* H;
    float* att;
};

template <int K, int HEADS>
__global__ __launch_bounds__(256, 2) void gemm_att_kernel(
    GemmArgs g0, GemmArgs g1, GemmArgs g2, GemmArgs g3, int N) {
    const GemmArgs ga[4] = {g0, g1, g2, g3};
    const GemmArgs g = ga[blockIdx.y];
    constexpr int XS_STRIDE = 33;
    constexpr int XS_BUF = 128 * XS_STRIDE;     // 4224 floats per buffer
    constexpr int WS_STRIDE = 28;               // 112B rows -> 16B aligned slices
    constexpr int WS_WAVE = 32 * WS_STRIDE;     // 896 floats per wave slice
    constexpr int WS_BUF = 4 * WS_WAVE;         // 3584 floats per buffer
    constexpr int SMEM_BYTES = (2 * XS_BUF + 2 * WS_BUF) * 4;  // 62464
    __shared__ __align__(16) char smem[SMEM_BYTES];
    const int tid = threadIdx.x;
    const int lane = tid & 63;
    const int w = tid >> 6;
    const int node0 = blockIdx.x * 128;
    const int nA = node0 + lane;
    const int nB = node0 + 64 + lane;
    const bool vA = nA < N, vB = nB < N;

    const int c0 = __builtin_amdgcn_readfirstlane(25 * w);  // wave-uniform

    float acc0[25], acc1[25];
#pragma unroll
    for (int j = 0; j < 25; ++j) { acc0[j] = 0.f; acc1[j] = 0.f; }

    float* Xs = (float*)smem;
    float* Wsh = (float*)smem + 2 * XS_BUF;
    float4 rv[4];
    float wv[13];

    auto issue_x = [&](int k0) {
#pragma unroll
        for (int r = 0; r < 4; ++r) {
            const int s = tid + r * 256;
            const int n = s >> 3;
            const int ko = (s & 7) * 4;
            int row = node0 + n;
            if (row >= N) row = N - 1;  // valid addr; values masked in epilogue
            const float* xp = g.X + (size_t)row * K + k0 + ko;
            if constexpr (K % 32 == 0) {
                rv[r] = *(const float4*)xp;
            } else {
                const int kb = k0 + ko;
                float4 v = make_float4(0.f, 0.f, 0.f, 0.f);
                if (kb + 3 < K) {
                    v = *(const float4*)xp;
                } else {
                    if (kb < K) v.x = xp[0];
                    if (kb + 1 < K) v.y = xp[1];
                    if (kb + 2 < K) v.z = xp[2];
                }
                rv[r] = v;
            }
        }
    };
    auto write_x = [&](int buf) {
#pragma unroll
        for (int r = 0; r < 4; ++r) {
            const int s = tid + r * 256;
            const int n = s >> 3;
            const int ko = (s & 7) * 4;
            float* dst = Xs + buf * XS_BUF + n * XS_STRIDE + ko;
            dst[0] = rv[r].x;
            dst[1] = rv[r].y;
            dst[2] = rv[r].z;
            dst[3] = rv[r].w;
        }
    };
    auto issue_w = [&](int k0, int kc) {
        const int lim = kc * 100;
#pragma unroll
        for (int r = 0; r < 13; ++r) {
            const int e = tid + r * 256;
            wv[r] = (e < lim) ? g.W[(size_t)k0 * 100 + e] : 0.f;
        }
    };
    auto write_w = [&](int buf, int kc) {
        const int lim = kc * 100;
#pragma unroll
        for (int r = 0; r < 13; ++r) {
            const int e = tid + r * 256;
            if (e < lim) {
                const int k = e / 100;
                const int j = e - k * 100;
                const int hd = j / 25;
                const int jj = j - hd * 25;
                Wsh[buf * WS_BUF + hd * WS_WAVE + k * WS_STRIDE + jj] = wv[r];
            }
        }
    };

    constexpr int C = (K + 31) / 32;
    {
        const int kc0 = (K < 32) ? K : 32;
        issue_x(0);
        issue_w(0, kc0);
        write_x(0);
        write_w(0, kc0);
    }
    __syncthreads();
    for (int c = 0; c < C; ++c) {
        const int k0 = c * 32;
        const int kc = (K - k0 < 32) ? (K - k0) : 32;
        const int kcn = (K - k0 - 32 < 32) ? (K - k0 - 32) : 32;
        if (c + 1 < C) {
            issue_x(k0 + 32);
            issue_w(k0 + 32, kcn);
        }
        const float* x0p = Xs + (c & 1) * XS_BUF + lane * XS_STRIDE;
        const float* x1p = x0p + 64 * XS_STRIDE;
        const float* wp = Wsh + (c & 1) * WS_BUF + w * WS_WAVE;
#pragma unroll 4
        for (int kk = 0; kk < kc; ++kk) {
            const float xs0 = x0p[kk];
            const float xs1 = x1p[kk];
            float wr[25];
#pragma unroll
            for (int j = 0; j < 25; ++j) wr[j] = wp[kk * WS_STRIDE + j];
#pragma unroll
            for (int j = 0; j < 25; ++j) {
                acc0[j] = fmaf(xs0, wr[j], acc0[j]);
                acc1[j] = fmaf(xs1, wr[j], acc1[j]);
            }
        }
        if (c + 1 < C) {
            __syncthreads();  // all waves done reading buf (c+1)&1 before overwrite
            write_x((c + 1) & 1);
            write_w((c + 1) & 1, kcn);
        }
        __syncthreads();
    }

    float ap0 = 0.f, ap1 = 0.f;
#pragma unroll
    for (int j = 0; j < 25; ++j) {
        const float av = g.a[c0 + j];
        ap0 = fmaf(acc0[j], av, ap0);
        ap1 = fmaf(acc1[j], av, ap1);
    }

    const int rem = N - node0;
    if (HEADS == 4) {
        if (g.H == nullptr) {  // dst role: a_dst only
            if (vA) g.att[(size_t)nA * 4 + w] = ap0;
            if (vB) g.att[(size_t)nB * 4 + w] = ap1;
        } else {               // src role: packed bf16 rows [104], LDS stride 106 (odd uints)
            u16* sh = (u16*)smem;
            u32* sh32 = (u32*)smem;
            // chunk A
#pragma unroll
            for (int j = 0; j < 25; ++j) sh[lane * 106 + c0 + j] = f2b(acc0[j]);
            sh[lane * 106 + 100 + w] = f2b(ap0);
            __syncthreads();
            {
                const int limA = ((rem < 64) ? rem : 64) * 52;
                u32* Hb = (u32*)g.H + (size_t)node0 * 52;
                for (int i = tid; i < 64 * 52; i += 256) {
                    if (i < limA) {
                        int nd = i / 52;
                        Hb[i] = sh32[nd * 53 + (i - nd * 52)];
                    }
                }
            }
            __syncthreads();
            // chunk B
#pragma unroll
            for (int j = 0; j < 25; ++j) sh[lane * 106 + c0 + j] = f2b(acc1[j]);
            sh[lane * 106 + 100 + w] = f2b(ap1);
            __syncthreads();
            {
                const int remB = rem - 64;
                const int limB = ((remB < 64) ? (remB < 0 ? 0 : remB) : 64) * 52;
                u32* Hb = (u32*)g.H + (size_t)(node0 + 64) * 52;
                for (int i = tid; i < 64 * 52; i += 256) {
                    if (i < limB) {
                        int nd = i / 52;
                        Hb[i] = sh32[nd * 53 + (i - nd * 52)];
                    }
                }
            }
        }
    } else {
        // HEADS==1: packed bf16 rows [100] (50 u32), LDS stride 102 u16 (51 u32, odd)
        u16* sh = (u16*)smem;
        u32* sh32 = (u32*)smem;
        float* attp = (float*)(smem + 64 * 102 * 2);
        attp[w * 128 + lane] = ap0;
        attp[w * 128 + 64 + lane] = ap1;
        if (g.H != nullptr) {
            // chunk A
#pragma unroll
            for (int j = 0; j < 25; ++j) sh[lane * 102 + c0 + j] = f2b(acc0[j]);
            __syncthreads();
            {
                const int limA = ((rem < 64) ? rem : 64) * 50;
                u32* Hb = (u32*)g.H + (size_t)node0 * 50;
                for (int i = tid; i < 64 * 50; i += 256) {
                    if (i < limA) {
                        int nd = i / 50;
                        Hb[i] = sh32[nd * 51 + (i - nd * 50)];
                    }
                }
                if (tid < 128 && node0 + tid < N)
                    g.att[node0 + tid] =
                        attp[tid] + attp[128 + tid] + attp[256 + tid] + attp[384 + tid];
            }
            __syncthreads();
            // chunk B
#pragma unroll
            for (int j = 0; j < 25; ++j) sh[lane * 102 + c0 + j] = f2b(acc1[j]);
            __syncthreads();
            {
                const int remB = rem - 64;
                const int limB = ((remB < 64) ? (remB < 0 ? 0 : remB) : 64) * 50;
                u32* Hb = (u32*)g.H + (size_t)(node0 + 64) * 50;
                for (int i = tid; i < 64 * 50; i += 256) {
                    if (i < limB) {
                        int nd = i / 50;
                        Hb[i] = sh32[nd * 51 + (i - nd * 50)];
                    }
                }
            }
        } else {
            __syncthreads();
            if (tid < 128 && node0 + tid < N)
                g.att[node0 + tid] =
                    attp[tid] + attp[128 + tid] + attp[256 + tid] + attp[384 + tid];
        }
    }
}

// ---------------- layer-1 gather: wave per dst node, packed bf16 src rows ----------------
// R12: scalar SMEM edge loads (ss/sw -> s_load via readfirstlane'd offsets; scalar row
// base; saddr value/a_src loads) + explicit 1-deep pipeline over 4-edge groups with
// named double buffers and sched_barrier(0) between load-issue and compute.
struct Gather4Args {
    const int* ro;
    const int* ss;
    const float* sw;
    const u16* hp;     // [Ns][104] bf16: 0..99 h, 100..103 a_src
    const float* ad;   // [Nd,4] fp32
    const float* ce;   // [4]
    const float* bias; // [100]
    float* outp;       // [Nd,100]
};

__global__ __launch_bounds__(256) void gather4_kernel(Gather4Args ga0, Gather4Args ga1, int Nd) {
    const Gather4Args ga[2] = {ga0, ga1};
    const Gather4Args g = ga[blockIdx.y];
    int wid = (int)((blockIdx.x * blockDim.x + threadIdx.x) >> 6);
    if (wid >= Nd) return;
    const int n = __builtin_amdgcn_readfirstlane(wid);
    const int lane = threadIdx.x & 63;
    const int beg = g.ro[n], end = g.ro[n + 1];
    const bool act = (lane < 50);
    const int cc0 = act ? 2 * lane : 0;   // channels (cc0, cc0+1)
    const int h0 = cc0 / 25;
    const int h1 = (cc0 + 1) / 25;        // == h0 or h0+1 (h0 even at boundaries)
    const int aoff = 2 * (h0 >> 1);       // u16 off 100+aoff holds heads (h0&~1, h0&~1+1)
    const float ce0 = g.ce[h0], ce1 = g.ce[h1];
    const float ad0 = g.ad[n * 4 + h0], ad1 = g.ad[n * 4 + h1];
    float acc0 = 0.f, acc1 = 0.f, d0 = 0.f, d1 = 0.f;

    auto edge = [&](u32 va, u32 aa, float wq, float& p0o, float& p1o) {
        const float as0 = b2f((h0 & 1) ? (u16)(aa >> 16) : (u16)aa);
        const float as1 = b2f((h1 & 1) ? (u16)(aa >> 16) : (u16)aa);
        float l0 = as0 + ad0 + wq * ce0;
        float l1 = as1 + ad1 + wq * ce1;
        l0 = fmaxf(l0, 0.2f * l0);
        l1 = fmaxf(l1, 0.2f * l1);
        const float p0 = __expf(l0);
        const float p1 = __expf(l1);
        acc0 = fmaf(p0, b2f((u16)va), acc0);
        acc1 = fmaf(p1, b2f((u16)(va >> 16)), acc1);
        p0o = p0;
        p1o = p1;
    };

    struct G4 { u32 va0, aa0, va1, aa1, va2, aa2, va3, aa3; float w0, w1, w2, w3; };
    auto load4 = [&](int off) -> G4 {
        G4 r;
        const int o = __builtin_amdgcn_readfirstlane(off);
        const int s0 = g.ss[o];
        const int s1 = g.ss[o + 1];
        const int s2 = g.ss[o + 2];
        const int s3 = g.ss[o + 3];
        r.w0 = g.sw[o];
        r.w1 = g.sw[o + 1];
        r.w2 = g.sw[o + 2];
        r.w3 = g.sw[o + 3];
        const u16* r0 = g.hp + (size_t)s0 * 104;
        const u16* r1 = g.hp + (size_t)s1 * 104;
        const u16* r2 = g.hp + (size_t)s2 * 104;
        const u16* r3 = g.hp + (size_t)s3 * 104;
        r.va0 = *(const u32*)(r0 + cc0);
        r.aa0 = *(const u32*)(r0 + 100 + aoff);
        r.va1 = *(const u32*)(r1 + cc0);
        r.aa1 = *(const u32*)(r1 + 100 + aoff);
        r.va2 = *(const u32*)(r2 + cc0);
        r.aa2 = *(const u32*)(r2 + 100 + aoff);
        r.va3 = *(const u32*)(r3 + cc0);
        r.aa3 = *(const u32*)(r3 + 100 + aoff);
        return r;
    };
    auto compute4 = [&](const G4& e) {
        float pa0, pa1, pb0, pb1;
        edge(e.va0, e.aa0, e.w0, pa0, pa1);
        edge(e.va1, e.aa1, e.w1, pb0, pb1);
        d0 += pa0 + pb0;
        d1 += pa1 + pb1;
        edge(e.va2, e.aa2, e.w2, pa0, pa1);
        edge(e.va3, e.aa3, e.w3, pb0, pb1);
        d0 += pa0 + pb0;
        d1 += pa1 + pb1;
    };

    int i = beg;
    const int last4 = beg + ((end - beg) & ~3);
    if (i < last4) {
        G4 cur = load4(i);
        i += 4;
        for (; i < last4; i += 4) {
            G4 nxt = load4(i);
            __builtin_amdgcn_sched_barrier(0);  // keep prefetch above compute
            compute4(cur);
            cur = nxt;
        }
        compute4(cur);
    }
    if (i + 1 < end) {  // 2-3 remain -> pair (matches R11 chunk-tail pairing)
        const int o = __builtin_amdgcn_readfirstlane(i);
        const int s0 = g.ss[o], s1 = g.ss[o + 1];
        const float w0 = g.sw[o], w1 = g.sw[o + 1];
        const u16* r0 = g.hp + (size_t)s0 * 104;
        const u16* r1 = g.hp + (size_t)s1 * 104;
        const u32 va0 = *(const u32*)(r0 + cc0);
        const u32 aa0 = *(const u32*)(r0 + 100 + aoff);
        const u32 va1 = *(const u32*)(r1 + cc0);
        const u32 aa1 = *(const u32*)(r1 + 100 + aoff);
        float pa0, pa1, pb0, pb1;
        edge(va0, aa0, w0, pa0, pa1);
        edge(va1, aa1, w1, pb0, pb1);
        d0 += pa0 + pb0;
        d1 += pa1 + pb1;
        i += 2;
    }
    if (i < end) {  // single
        const int o = __builtin_amdgcn_readfirstlane(i);
        const int s0 = g.ss[o];
        const float w0 = g.sw[o];
        const u16* r0 = g.hp + (size_t)s0 * 104;
        const u32 va0 = *(const u32*)(r0 + cc0);
        const u32 aa0 = *(const u32*)(r0 + 100 + aoff);
        float pa0, pa1;
        edge(va0, aa0, w0, pa0, pa1);
        d0 += pa0;
        d1 += pa1;
    }

    if (act) {
        float r0 = (end > beg) ? acc0 / d0 : 0.f;
        float r1 = (end > beg) ? acc1 / d1 : 0.f;
        r0 += g.bias[cc0];
        r0 = (r0 > 0.f) ? r0 : (__expf(r0) - 1.f);  // elu
        r1 += g.bias[cc0 + 1];
        r1 = (r1 > 0.f) ? r1 : (__expf(r1) - 1.f);
        *(float2*)(g.outp + (size_t)n * 100 + cc0) = make_float2(r0, r1);
    }
}

// ---------------- layer-2 gather: wave per dst node, heads=1, ch=100, bf16 rows ----------------
// R12: same scalar-load + pipelined structure; as_ logit is a scalar s_load per edge.
struct Gather1Args {
    const int* ro;
    const int* ss;
    const u16* hp;     // [Ns][100] bf16
    const float* as_;  // [Ns] fp32
    const float* ad;   // [Nd] fp32
    const float* bias; // [100]
    float* outp;       // [Nd,100]
};

__global__ __launch_bounds__(256) void gather1_kernel(Gather1Args ga0, Gather1Args ga1, int Nd) {
    const Gather1Args ga[2] = {ga0, ga1};
    const Gather1Args g = ga[blockIdx.y];
    int wid = (int)((blockIdx.x * blockDim.x + threadIdx.x) >> 6);
    if (wid >= Nd) return;
    const int n = __builtin_amdgcn_readfirstlane(wid);
    const int lane = threadIdx.x & 63;
    const int beg = g.ro[n], end = g.ro[n + 1];
    const bool act = (lane < 50);
    const int cc0 = act ? 2 * lane : 0;
    const float adn = g.ad[n];
    float acc0 = 0.f, acc1 = 0.f, d0 = 0.f;

    auto edge = [&](u32 va, float asq, float& po) {
        float l = asq + adn;
        l = fmaxf(l, 0.2f * l);
        const float p = __expf(l);
        acc0 = fmaf(p, b2f((u16)va), acc0);
        acc1 = fmaf(p, b2f((u16)(va >> 16)), acc1);
        po = p;
    };

    struct G1 { u32 va0, va1, va2, va3; float a0, a1, a2, a3; };
    auto load4 = [&](int off) -> G1 {
        G1 r;
        const int o = __builtin_amdgcn_readfirstlane(off);
        const int s0 = g.ss[o];
        const int s1 = g.ss[o + 1];
        const int s2 = g.ss[o + 2];
        const int s3 = g.ss[o + 3];
        r.a0 = g.as_[s0];
        r.a1 = g.as_[s1];
        r.a2 = g.as_[s2];
        r.a3 = g.as_[s3];
        r.va0 = *(const u32*)(g.hp + (size_t)s0 * 100 + cc0);
        r.va1 = *(const u32*)(g.hp + (size_t)s1 * 100 + cc0);
        r.va2 = *(const u32*)(g.hp + (size_t)s2 * 100 + cc0);
        r.va3 = *(const u32*)(g.hp + (size_t)s3 * 100 + cc0);
        return r;
    };
    auto compute4 = [&](const G1& e) {
        float pa, pb;
        edge(e.va0, e.a0, pa);
        edge(e.va1, e.a1, pb);
        d0 += pa + pb;
        edge(e.va2, e.a2, pa);
        edge(e.va3, e.a3, pb);
        d0 += pa + pb;
    };

    int i = beg;
    const int last4 = beg + ((end - beg) & ~3);
    if (i < last4) {
        G1 cur = load4(i);
        i += 4;
        for (; i < last4; i += 4) {
            G1 nxt = load4(i);
            __builtin_amdgcn_sched_barrier(0);  // keep prefetch above compute
            compute4(cur);
            cur = nxt;
        }
        compute4(cur);
    }
    if (i + 1 < end) {  // 2-3 remain -> pair
        const int o = __builtin_amdgcn_readfirstlane(i);
        const int s0 = g.ss[o], s1 = g.ss[o + 1];
        const float a0 = g.as_[s0], a1 = g.as_[s1];
        const u32 va0 = *(const u32*)(g.hp + (size_t)s0 * 100 + cc0);
        const u32 va1 = *(const u32*)(g.hp + (size_t)s1 * 100 + cc0);
        float pa, pb;
        edge(va0, a0, pa);
        edge(va1, a1, pb);
        d0 += pa + pb;
        i += 2;
    }
    if (i < end) {  // single
        const int o = __builtin_amdgcn_readfirstlane(i);
        const int s0 = g.ss[o];
        const float a0 = g.as_[s0];
        const u32 va0 = *(const u32*)(g.hp + (size_t)s0 * 100 + cc0);
        float pa;
        edge(va0, a0, pa);
        d0 += pa;
    }

    if (act) {
        float r0 = (end > beg) ? acc0 / d0 : 0.f;
        float r1 = (end > beg) ? acc1 / d0 : 0.f;
        r0 += g.bias[cc0];
        r1 += g.bias[cc0 + 1];
        *(float2*)(g.outp + (size_t)n * 100 + cc0) = make_float2(r0, r1);
    }
}

extern "C" void kernel_launch(void* const* d_in, const int* in_sizes, int n_in,
                              void* d_out, int out_size, void* d_ws, size_t ws_size,
                              hipStream_t stream) {
    const float* x_A   = (const float*)d_in[0];
    const float* x_B   = (const float*)d_in[1];
    const int*   ei_AB = (const int*)d_in[2];
    const int*   ei_BA = (const int*)d_in[3];
    const float* w_AB  = (const float*)d_in[4];
    const float* w_BA  = (const float*)d_in[5];
    const float* l1AB_Ws = (const float*)d_in[6];
    const float* l1AB_Wd = (const float*)d_in[7];
    const float* l1AB_as = (const float*)d_in[8];
    const float* l1AB_ad = (const float*)d_in[9];
    const float* l1AB_We = (const float*)d_in[10];
    const float* l1AB_ae = (const float*)d_in[11];
    const float* l1AB_b  = (const float*)d_in[12];
    const float* l2AB_Ws = (const float*)d_in[13];
    const float* l2AB_Wd = (const float*)d_in[14];
    const float* l2AB_as = (const float*)d_in[15];
    const float* l2AB_ad = (const float*)d_in[16];
    const float* l2AB_b  = (const float*)d_in[17];
    const float* l1BA_Ws = (const float*)d_in[18];
    const float* l1BA_Wd = (const float*)d_in[19];
    const float* l1BA_as = (const float*)d_in[20];
    const float* l1BA_ad = (const float*)d_in[21];
    const float* l1BA_We = (const float*)d_in[22];
    const float* l1BA_ae = (const float*)d_in[23];
    const float* l1BA_b  = (const float*)d_in[24];
    const float* l2BA_Ws = (const float*)d_in[25];
    const float* l2BA_Wd = (const float*)d_in[26];
    const float* l2BA_as = (const float*)d_in[27];
    const float* l2BA_ad = (const float*)d_in[28];
    const float* l2BA_b  = (const float*)d_in[29];

    const int N = NNODES, E = NEDGES;

    // ---- workspace carve (4-byte elements, 64-element aligned) ----
    size_t o = 0;
    auto alloc = [&](size_t n) { size_t r = o; o += (n + 63) & ~(size_t)63; return r; };
    size_t cntA = alloc(N), cntB = alloc(N);
    size_t roA = alloc(N + 1), roB = alloc(N + 1);
    size_t curA = alloc(N), curB = alloc(N);
    size_t ssA = alloc(E), ssB = alloc(E);
    size_t swA = alloc(E), swB = alloc(E);
    size_t ce8 = alloc(8);
    size_t part = alloc(128);
    size_t pHAB = alloc((size_t)N * 52);  // packed bf16 [N][104] as uints
    size_t pHBA = alloc((size_t)N * 52);
    size_t ad1B = alloc((size_t)N * 4), ad1A = alloc((size_t)N * 4);
    size_t hA1 = alloc((size_t)N * 100), hB1 = alloc((size_t)N * 100);
    size_t H2AB = alloc((size_t)N * 50);  // packed bf16 [N][100] as uints
    size_t H2BA = alloc((size_t)N * 50);
    size_t as2AB = alloc(N), as2BA = alloc(N);
    size_t ad2AB = alloc(N), ad2BA = alloc(N);
    (void)ws_size;

    float* wsf = (float*)d_ws;
    int*   wsi = (int*)d_ws;
    u32*   wsu = (u32*)d_ws;

    // zero edge-count histograms (cntA..cntB contiguous span)
    hipMemsetAsync(wsi + cntA, 0, sizeof(int) * (cntB + N - cntA), stream);

    ce_kernel<<<2, 128, 0, stream>>>(l1AB_We, l1AB_ae, l1BA_We, l1BA_ae, wsf + ce8);

    const int eb = (2 * E + 255) / 256;
    count_kernel<<<eb, 256, 0, stream>>>(ei_AB, ei_BA, E, wsi + cntA, wsi + cntB);
    scanA_kernel<<<dim3(SCAN_NBLK, 2), SCAN_T, 0, stream>>>(
        wsi + cntA, wsi + cntB, wsi + roA, wsi + roB, wsi + part, N);
    scanB_kernel<<<1, 128, 0, stream>>>(wsi + part, SCAN_NBLK);
    scanC_kernel<<<dim3(SCAN_NBLK, 2), SCAN_T, 0, stream>>>(
        wsi + cntA, wsi + cntB, wsi + roA, wsi + roB, wsi + curA, wsi + curB, wsi + part, N);
    fill_kernel<<<eb, 256, 0, stream>>>(ei_AB, ei_BA, w_AB, w_BA, E, wsi + curA, wsi + curB,
                                        wsi + ssA, wsi + ssB, wsf + swA, wsf + swB);

    const int gb = (N + 127) / 128;  // 391
    // layer-1 node transforms (src roles -> packed bf16 tables; dst roles -> a_dst only)
    {
        GemmArgs g0 = {x_A, l1AB_Ws, l1AB_as, (void*)(wsu + pHAB), nullptr};
        GemmArgs g1 = {x_B, l1AB_Wd, l1AB_ad, nullptr, wsf + ad1B};
        GemmArgs g2 = {x_B, l1BA_Ws, l1BA_as, (void*)(wsu + pHBA), nullptr};
        GemmArgs g3 = {x_A, l1BA_Wd, l1BA_ad, nullptr, wsf + ad1A};
        gemm_att_kernel<128, 4><<<dim3(gb, 4), 256, 0, stream>>>(g0, g1, g2, g3, N);
    }

    const int wb = (N + 3) / 4;  // wave per node, 4 waves/block
    {
        Gather4Args g0 = {wsi + roA, wsi + ssA, wsf + swA, (const u16*)(wsu + pHAB),
                          wsf + ad1B, wsf + ce8, l1AB_b, wsf + hB1};
        Gather4Args g1 = {wsi + roB, wsi + ssB, wsf + swB, (const u16*)(wsu + pHBA),
                          wsf + ad1A, wsf + ce8 + 4, l1BA_b, wsf + hA1};
        gather4_kernel<<<dim3(wb, 2), 256, 0, stream>>>(g0, g1, N);
    }

    // layer-2 node transforms (src roles -> packed bf16 H + as; dst roles -> ad only)
    {
        GemmArgs g0 = {wsf + hA1, l2AB_Ws, l2AB_as, (void*)(wsu + H2AB), wsf + as2AB};
        GemmArgs g1 = {wsf + hB1, l2AB_Wd, l2AB_ad, nullptr, wsf + ad2AB};
        GemmArgs g2 = {wsf + hB1, l2BA_Ws, l2BA_as, (void*)(wsu + H2BA), wsf + as2BA};
        GemmArgs g3 = {wsf + hA1, l2BA_Wd, l2BA_ad, nullptr, wsf + ad2BA};
        gemm_att_kernel<100, 1><<<dim3(gb, 4), 256, 0, stream>>>(g0, g1, g2, g3, N);
    }

    float* out = (float*)d_out;
    // oA = BA direction (dst in A) -> d_out[0..5M); oB = AB direction -> d_out[5M..10M)
    {
        Gather1Args g0 = {wsi + roA, wsi + ssA, (const u16*)(wsu + H2AB), wsf + as2AB,
                          wsf + ad2AB, l2AB_b, out + (size_t)N * 100};
        Gather1Args g1 = {wsi + roB, wsi + ssB, (const u16*)(wsu + H2BA), wsf + as2BA,
                          wsf + ad2BA, l2BA_b, out};
        gather1_kernel<<<dim3(wb, 2), 256, 0, stream>>>(g0, g1, N);
    }
}

// Round 9
// 921.188 us; speedup vs baseline: 1.0786x; 1.0330x over previous
//
#include <hip/hip_runtime.h>

// HeteroGAT: 2-layer bipartite GAT (heads=4,ch=25 concat + edge feat; then heads=1,ch=100).
// R6: layer-1 gather HBM-bound -> packed bf16 src tables.
// R7: layer-2 src tables bf16 (-27us; cache-absorbed).
// R8/R9: gemm X+W staged via LDS -> 1213->991us.
// R10-R12: three ILP passes on gather4: 271->240us total (~5% each). Counters: FETCH
//      334MB = exactly 208B/edge (minimal bytes), VALU 39%, ~92 CU-cyc/edge -> cost
//      tracks random LINE TRANSACTIONS (208B rows straddle ~2.6 lines), not bytes.
// R13: (a) pad table rows to 256B (128 u16): every row = exactly 2 aligned lines;
//          tx/edge ~3 -> 2. Same for layer-2 table. Epilogue stride 52->64 u32.
//      (b) 2-deep group pipeline (8 edges in flight) with named buffers + sched_barrier.
//      Edge order / fma sequence verbatim -> absmax unchanged (0.00390625).

#define NNODES 50000
#define NEDGES 800000
#define SCAN_T 1024
#define SCAN_NBLK ((NNODES + SCAN_T - 1) / SCAN_T)  // 49

typedef unsigned short u16;
typedef unsigned int u32;

__device__ __forceinline__ float b2f(u16 u) {
    union { u32 i; float f; } x;
    x.i = ((u32)u) << 16;
    return x.f;
}
__device__ __forceinline__ u16 f2b(float f) {  // RN-even
    union { float f; u32 i; } x;
    x.f = f;
    u32 r = x.i + 0x7FFFu + ((x.i >> 16) & 1u);
    return (u16)(r >> 16);
}

// ---------------- ce[h] = sum_c We[h*25+c]*ae[h*25+c] (edge-attn constant) ----------------
__global__ void ce_kernel(const float* __restrict__ WeA, const float* __restrict__ aeA,
                          const float* __restrict__ WeB, const float* __restrict__ aeB,
                          float* __restrict__ ce /*[8]: 0..3=AB, 4..7=BA*/) {
    const float* We = blockIdx.x ? WeB : WeA;
    const float* ae = blockIdx.x ? aeB : aeA;
    __shared__ float s[4];
    int tid = threadIdx.x;
    if (tid < 4) s[tid] = 0.f;
    __syncthreads();
    if (tid < 100) atomicAdd(&s[tid / 25], We[tid] * ae[tid]);
    __syncthreads();
    if (tid < 4) ce[blockIdx.x * 4 + tid] = s[tid];
}

// ---------------- CSR build ----------------
__global__ void count_kernel(const int* __restrict__ eiA, const int* __restrict__ eiB,
                             int E, int* cntA, int* cntB) {
    int i = blockIdx.x * blockDim.x + threadIdx.x;
    if (i < E) atomicAdd(&cntA[eiA[E + i]], 1);
    else if (i < 2 * E) atomicAdd(&cntB[eiB[E + (i - E)]], 1);
}

__global__ __launch_bounds__(SCAN_T) void scanA_kernel(
    const int* __restrict__ cntA, const int* __restrict__ cntB,
    int* __restrict__ roA, int* __restrict__ roB, int* __restrict__ partial, int N) {
    const int dir = blockIdx.y;
    const int* cnt = dir ? cntB : cntA;
    int* ro = dir ? roB : roA;
    const int tid = threadIdx.x;
    const int i = blockIdx.x * SCAN_T + tid;
    __shared__ int sm[SCAN_T];
    sm[tid] = (i < N) ? cnt[i] : 0;
    __syncthreads();
    for (int off = 1; off < SCAN_T; off <<= 1) {
        int t = (tid >= off) ? sm[tid - off] : 0;
        __syncthreads();
        sm[tid] += t;
        __syncthreads();
    }
    if (i < N) ro[i + 1] = sm[tid];
    if (tid == SCAN_T - 1) partial[dir * 64 + blockIdx.x] = sm[tid];
}

__global__ void scanB_kernel(int* __restrict__ partial, int nblk) {
    __shared__ int sm[128];
    const int tid = threadIdx.x;
    sm[tid] = ((tid & 63) < nblk) ? partial[tid] : 0;
    __syncthreads();
    if (tid < 2) {
        int run = 0;
        for (int b = 0; b < nblk; ++b) {
            int t = sm[tid * 64 + b];
            sm[tid * 64 + b] = run;
            run += t;
        }
    }
    __syncthreads();
    partial[tid] = sm[tid];
}

__global__ __launch_bounds__(SCAN_T) void scanC_kernel(
    const int* __restrict__ cntA, const int* __restrict__ cntB,
    int* __restrict__ roA, int* __restrict__ roB,
    int* __restrict__ curA, int* __restrict__ curB,
    const int* __restrict__ partial, int N) {
    const int dir = blockIdx.y;
    const int* cnt = dir ? cntB : cntA;
    int* ro = dir ? roB : roA;
    int* cur = dir ? curB : curA;
    const int poff = partial[dir * 64 + blockIdx.x];
    const int i = blockIdx.x * SCAN_T + threadIdx.x;
    if (i < N) {
        int c = cnt[i];
        int r = ro[i + 1] + poff;
        ro[i + 1] = r;
        cur[i] = r - c;
        if (i == 0) ro[0] = 0;
    }
}

__global__ void fill_kernel(const int* __restrict__ eiA, const int* __restrict__ eiB,
                            const float* __restrict__ wA, const float* __restrict__ wB,
                            int E, int* curA, int* curB,
                            int* __restrict__ ssA, int* __restrict__ ssB,
                            float* __restrict__ swA, float* __restrict__ swB) {
    int i = blockIdx.x * blockDim.x + threadIdx.x;
    if (i < E) {
        int s = eiA[i], d = eiA[E + i];
        int pos = atomicAdd(&curA[d], 1);
        ssA[pos] = s; swA[pos] = wA[i];
    } else if (i < 2 * E) {
        int j = i - E;
        int s = eiB[j], d = eiB[E + j];
        int pos = atomicAdd(&curB[d], 1);
        ssB[pos] = s; swB[pos] = wB[j];
    }
}

// ---------------- GEMM [N,K]x[K,100] + fused att ----------------
// 128 nodes/block; lane owns nodes (lane, lane+64); wave w owns cols [25w,25w+25).
// R8/R9: BOTH operands staged via LDS per 32-wide K-chunk, double-buffered.
// R13: packed-table output rows padded to 256B (node stride 64 u32).
struct GemmArgs {
    const float* X;
    const float* W;
    const float* a;
    void* H;
    float* att;
};

template <int K, int HEADS>
__global__ __launch_bounds__(256, 2) void gemm_att_kernel(
    GemmArgs g0, GemmArgs g1, GemmArgs g2, GemmArgs g3, int N) {
    const GemmArgs ga[4] = {g0, g1, g2, g3};
    const GemmArgs g = ga[blockIdx.y];
    constexpr int XS_STRIDE = 33;
    constexpr int XS_BUF = 128 * XS_STRIDE;     // 4224 floats per buffer
    constexpr int WS_STRIDE = 28;               // 112B rows -> 16B aligned slices
    constexpr int WS_WAVE = 32 * WS_STRIDE;     // 896 floats per wave slice
    constexpr int WS_BUF = 4 * WS_WAVE;         // 3584 floats per buffer
    constexpr int SMEM_BYTES = (2 * XS_BUF + 2 * WS_BUF) * 4;  // 62464
    __shared__ __align__(16) char smem[SMEM_BYTES];
    const int tid = threadIdx.x;
    const int lane = tid & 63;
    const int w = tid >> 6;
    const int node0 = blockIdx.x * 128;
    const int nA = node0 + lane;
    const int nB = node0 + 64 + lane;
    const bool vA = nA < N, vB = nB < N;

    const int c0 = __builtin_amdgcn_readfirstlane(25 * w);  // wave-uniform

    float acc0[25], acc1[25];
#pragma unroll
    for (int j = 0; j < 25; ++j) { acc0[j] = 0.f; acc1[j] = 0.f; }

    float* Xs = (float*)smem;
    float* Wsh = (float*)smem + 2 * XS_BUF;
    float4 rv[4];
    float wv[13];

    auto issue_x = [&](int k0) {
#pragma unroll
        for (int r = 0; r < 4; ++r) {
            const int s = tid + r * 256;
            const int n = s >> 3;
            const int ko = (s & 7) * 4;
            int row = node0 + n;
            if (row >= N) row = N - 1;  // valid addr; values masked in epilogue
            const float* xp = g.X + (size_t)row * K + k0 + ko;
            if constexpr (K % 32 == 0) {
                rv[r] = *(const float4*)xp;
            } else {
                const int kb = k0 + ko;
                float4 v = make_float4(0.f, 0.f, 0.f, 0.f);
                if (kb + 3 < K) {
                    v = *(const float4*)xp;
                } else {
                    if (kb < K) v.x = xp[0];
                    if (kb + 1 < K) v.y = xp[1];
                    if (kb + 2 < K) v.z = xp[2];
                }
                rv[r] = v;
            }
        }
    };
    auto write_x = [&](int buf) {
#pragma unroll
        for (int r = 0; r < 4; ++r) {
            const int s = tid + r * 256;
            const int n = s >> 3;
            const int ko = (s & 7) * 4;
            float* dst = Xs + buf * XS_BUF + n * XS_STRIDE + ko;
            dst[0] = rv[r].x;
            dst[1] = rv[r].y;
            dst[2] = rv[r].z;
            dst[3] = rv[r].w;
        }
    };
    auto issue_w = [&](int k0, int kc) {
        const int lim = kc * 100;
#pragma unroll
        for (int r = 0; r < 13; ++r) {
            const int e = tid + r * 256;
            wv[r] = (e < lim) ? g.W[(size_t)k0 * 100 + e] : 0.f;
        }
    };
    auto write_w = [&](int buf, int kc) {
        const int lim = kc * 100;
#pragma unroll
        for (int r = 0; r < 13; ++r) {
            const int e = tid + r * 256;
            if (e < lim) {
                const int k = e / 100;
                const int j = e - k * 100;
                const int hd = j / 25;
                const int jj = j - hd * 25;
                Wsh[buf * WS_BUF + hd * WS_WAVE + k * WS_STRIDE + jj] = wv[r];
            }
        }
    };

    constexpr int C = (K + 31) / 32;
    {
        const int kc0 = (K < 32) ? K : 32;
        issue_x(0);
        issue_w(0, kc0);
        write_x(0);
        write_w(0, kc0);
    }
    __syncthreads();
    for (int c = 0; c < C; ++c) {
        const int k0 = c * 32;
        const int kc = (K - k0 < 32) ? (K - k0) : 32;
        const int kcn = (K - k0 - 32 < 32) ? (K - k0 - 32) : 32;
        if (c + 1 < C) {
            issue_x(k0 + 32);
            issue_w(k0 + 32, kcn);
        }
        const float* x0p = Xs + (c & 1) * XS_BUF + lane * XS_STRIDE;
        const float* x1p = x0p + 64 * XS_STRIDE;
        const float* wp = Wsh + (c & 1) * WS_BUF + w * WS_WAVE;
#pragma unroll 4
        for (int kk = 0; kk < kc; ++kk) {
            const float xs0 = x0p[kk];
            const float xs1 = x1p[kk];
            float wr[25];
#pragma unroll
            for (int j = 0; j < 25; ++j) wr[j] = wp[kk * WS_STRIDE + j];
#pragma unroll
            for (int j = 0; j < 25; ++j) {
                acc0[j] = fmaf(xs0, wr[j], acc0[j]);
                acc1[j] = fmaf(xs1, wr[j], acc1[j]);
            }
        }
        if (c + 1 < C) {
            __syncthreads();  // all waves done reading buf (c+1)&1 before overwrite
            write_x((c + 1) & 1);
            write_w((c + 1) & 1, kcn);
        }
        __syncthreads();
    }

    float ap0 = 0.f, ap1 = 0.f;
#pragma unroll
    for (int j = 0; j < 25; ++j) {
        const float av = g.a[c0 + j];
        ap0 = fmaf(acc0[j], av, ap0);
        ap1 = fmaf(acc1[j], av, ap1);
    }

    const int rem = N - node0;
    if (HEADS == 4) {
        if (g.H == nullptr) {  // dst role: a_dst only
            if (vA) g.att[(size_t)nA * 4 + w] = ap0;
            if (vB) g.att[(size_t)nB * 4 + w] = ap1;
        } else {  // src role: rows of 128 u16 (104 payload), node stride 64 u32
            u16* sh = (u16*)smem;
            u32* sh32 = (u32*)smem;
            // chunk A
#pragma unroll
            for (int j = 0; j < 25; ++j) sh[lane * 106 + c0 + j] = f2b(acc0[j]);
            sh[lane * 106 + 100 + w] = f2b(ap0);
            __syncthreads();
            {
                const int limA = ((rem < 64) ? rem : 64) * 52;
                u32* Hb = (u32*)g.H + (size_t)node0 * 64;
                for (int i = tid; i < 64 * 52; i += 256) {
                    if (i < limA) {
                        int nd = i / 52;
                        int off = i - nd * 52;
                        Hb[nd * 64 + off] = sh32[nd * 53 + off];
                    }
                }
            }
            __syncthreads();
            // chunk B
#pragma unroll
            for (int j = 0; j < 25; ++j) sh[lane * 106 + c0 + j] = f2b(acc1[j]);
            sh[lane * 106 + 100 + w] = f2b(ap1);
            __syncthreads();
            {
                const int remB = rem - 64;
                const int limB = ((remB < 64) ? (remB < 0 ? 0 : remB) : 64) * 52;
                u32* Hb = (u32*)g.H + (size_t)(node0 + 64) * 64;
                for (int i = tid; i < 64 * 52; i += 256) {
                    if (i < limB) {
                        int nd = i / 52;
                        int off = i - nd * 52;
                        Hb[nd * 64 + off] = sh32[nd * 53 + off];
                    }
                }
            }
        }
    } else {
        // HEADS==1: rows of 128 u16 (100 payload), node stride 64 u32
        u16* sh = (u16*)smem;
        u32* sh32 = (u32*)smem;
        float* attp = (float*)(smem + 64 * 102 * 2);
        attp[w * 128 + lane] = ap0;
        attp[w * 128 + 64 + lane] = ap1;
        if (g.H != nullptr) {
            // chunk A
#pragma unroll
            for (int j = 0; j < 25; ++j) sh[lane * 102 + c0 + j] = f2b(acc0[j]);
            __syncthreads();
            {
                const int limA = ((rem < 64) ? rem : 64) * 50;
                u32* Hb = (u32*)g.H + (size_t)node0 * 64;
                for (int i = tid; i < 64 * 50; i += 256) {
                    if (i < limA) {
                        int nd = i / 50;
                        int off = i - nd * 50;
                        Hb[nd * 64 + off] = sh32[nd * 51 + off];
                    }
                }
                if (tid < 128 && node0 + tid < N)
                    g.att[node0 + tid] =
                        attp[tid] + attp[128 + tid] + attp[256 + tid] + attp[384 + tid];
            }
            __syncthreads();
            // chunk B
#pragma unroll
            for (int j = 0; j < 25; ++j) sh[lane * 102 + c0 + j] = f2b(acc1[j]);
            __syncthreads();
            {
                const int remB = rem - 64;
                const int limB = ((remB < 64) ? (remB < 0 ? 0 : remB) : 64) * 50;
                u32* Hb = (u32*)g.H + (size_t)(node0 + 64) * 64;
                for (int i = tid; i < 64 * 50; i += 256) {
                    if (i < limB) {
                        int nd = i / 50;
                        int off = i - nd * 50;
                        Hb[nd * 64 + off] = sh32[nd * 51 + off];
                    }
                }
            }
        } else {
            __syncthreads();
            if (tid < 128 && node0 + tid < N)
                g.att[node0 + tid] =
                    attp[tid] + attp[128 + tid] + attp[256 + tid] + attp[384 + tid];
        }
    }
}

// ---------------- layer-1 gather: wave per dst node, 256B-aligned bf16 src rows ----------------
// R12: scalar SMEM edge loads + pipelined 4-edge groups. R13: 256B rows (2 aligned
// lines/edge) + 2-deep pipeline (8 edges in flight).
struct Gather4Args {
    const int* ro;
    const int* ss;
    const float* sw;
    const u16* hp;     // [Ns][128] bf16: 0..99 h, 100..103 a_src, rest pad
    const float* ad;   // [Nd,4] fp32
    const float* ce;   // [4]
    const float* bias; // [100]
    float* outp;       // [Nd,100]
};

__global__ __launch_bounds__(256) void gather4_kernel(Gather4Args ga0, Gather4Args ga1, int Nd) {
    const Gather4Args ga[2] = {ga0, ga1};
    const Gather4Args g = ga[blockIdx.y];
    int wid = (int)((blockIdx.x * blockDim.x + threadIdx.x) >> 6);
    if (wid >= Nd) return;
    const int n = __builtin_amdgcn_readfirstlane(wid);
    const int lane = threadIdx.x & 63;
    const int beg = g.ro[n], end = g.ro[n + 1];
    const bool act = (lane < 50);
    const int cc0 = act ? 2 * lane : 0;   // channels (cc0, cc0+1)
    const int h0 = cc0 / 25;
    const int h1 = (cc0 + 1) / 25;        // == h0 or h0+1 (h0 even at boundaries)
    const int aoff = 2 * (h0 >> 1);       // u16 off 100+aoff holds heads (h0&~1, h0&~1+1)
    const float ce0 = g.ce[h0], ce1 = g.ce[h1];
    const float ad0 = g.ad[n * 4 + h0], ad1 = g.ad[n * 4 + h1];
    float acc0 = 0.f, acc1 = 0.f, d0 = 0.f, d1 = 0.f;

    auto edge = [&](u32 va, u32 aa, float wq, float& p0o, float& p1o) {
        const float as0 = b2f((h0 & 1) ? (u16)(aa >> 16) : (u16)aa);
        const float as1 = b2f((h1 & 1) ? (u16)(aa >> 16) : (u16)aa);
        float l0 = as0 + ad0 + wq * ce0;
        float l1 = as1 + ad1 + wq * ce1;
        l0 = fmaxf(l0, 0.2f * l0);
        l1 = fmaxf(l1, 0.2f * l1);
        const float p0 = __expf(l0);
        const float p1 = __expf(l1);
        acc0 = fmaf(p0, b2f((u16)va), acc0);
        acc1 = fmaf(p1, b2f((u16)(va >> 16)), acc1);
        p0o = p0;
        p1o = p1;
    };

    struct G4 { u32 va0, aa0, va1, aa1, va2, aa2, va3, aa3; float w0, w1, w2, w3; };
    auto load4 = [&](int off) -> G4 {
        G4 r;
        const int o = __builtin_amdgcn_readfirstlane(off);
        const int s0 = g.ss[o];
        const int s1 = g.ss[o + 1];
        const int s2 = g.ss[o + 2];
        const int s3 = g.ss[o + 3];
        r.w0 = g.sw[o];
        r.w1 = g.sw[o + 1];
        r.w2 = g.sw[o + 2];
        r.w3 = g.sw[o + 3];
        const u16* r0 = g.hp + (size_t)s0 * 128;
        const u16* r1 = g.hp + (size_t)s1 * 128;
        const u16* r2 = g.hp + (size_t)s2 * 128;
        const u16* r3 = g.hp + (size_t)s3 * 128;
        r.va0 = *(const u32*)(r0 + cc0);
        r.aa0 = *(const u32*)(r0 + 100 + aoff);
        r.va1 = *(const u32*)(r1 + cc0);
        r.aa1 = *(const u32*)(r1 + 100 + aoff);
        r.va2 = *(const u32*)(r2 + cc0);
        r.aa2 = *(const u32*)(r2 + 100 + aoff);
        r.va3 = *(const u32*)(r3 + cc0);
        r.aa3 = *(const u32*)(r3 + 100 + aoff);
        return r;
    };
    auto compute4 = [&](const G4& e) {
        float pa0, pa1, pb0, pb1;
        edge(e.va0, e.aa0, e.w0, pa0, pa1);
        edge(e.va1, e.aa1, e.w1, pb0, pb1);
        d0 += pa0 + pb0;
        d1 += pa1 + pb1;
        edge(e.va2, e.aa2, e.w2, pa0, pa1);
        edge(e.va3, e.aa3, e.w3, pb0, pb1);
        d0 += pa0 + pb0;
        d1 += pa1 + pb1;
    };

    int i = beg;
    const int last4 = beg + ((end - beg) & ~3);
    const int ng = (last4 - beg) >> 2;
    if (ng >= 2) {  // 2-deep pipeline
        G4 cur = load4(i);
        G4 nxt = load4(i + 4);
        i += 8;
        for (; i < last4; i += 4) {
            G4 nn = load4(i);
            __builtin_amdgcn_sched_barrier(0);  // keep prefetch above compute
            compute4(cur);
            cur = nxt;
            nxt = nn;
        }
        compute4(cur);
        compute4(nxt);
    } else if (ng == 1) {
        G4 cur = load4(i);
        compute4(cur);
        i += 4;
    }
    if (i + 1 < end) {  // 2-3 remain -> pair
        const int o = __builtin_amdgcn_readfirstlane(i);
        const int s0 = g.ss[o], s1 = g.ss[o + 1];
        const float w0 = g.sw[o], w1 = g.sw[o + 1];
        const u16* r0 = g.hp + (size_t)s0 * 128;
        const u16* r1 = g.hp + (size_t)s1 * 128;
        const u32 va0 = *(const u32*)(r0 + cc0);
        const u32 aa0 = *(const u32*)(r0 + 100 + aoff);
        const u32 va1 = *(const u32*)(r1 + cc0);
        const u32 aa1 = *(const u32*)(r1 + 100 + aoff);
        float pa0, pa1, pb0, pb1;
        edge(va0, aa0, w0, pa0, pa1);
        edge(va1, aa1, w1, pb0, pb1);
        d0 += pa0 + pb0;
        d1 += pa1 + pb1;
        i += 2;
    }
    if (i < end) {  // single
        const int o = __builtin_amdgcn_readfirstlane(i);
        const int s0 = g.ss[o];
        const float w0 = g.sw[o];
        const u16* r0 = g.hp + (size_t)s0 * 128;
        const u32 va0 = *(const u32*)(r0 + cc0);
        const u32 aa0 = *(const u32*)(r0 + 100 + aoff);
        float pa0, pa1;
        edge(va0, aa0, w0, pa0, pa1);
        d0 += pa0;
        d1 += pa1;
    }

    if (act) {
        float r0 = (end > beg) ? acc0 / d0 : 0.f;
        float r1 = (end > beg) ? acc1 / d1 : 0.f;
        r0 += g.bias[cc0];
        r0 = (r0 > 0.f) ? r0 : (__expf(r0) - 1.f);  // elu
        r1 += g.bias[cc0 + 1];
        r1 = (r1 > 0.f) ? r1 : (__expf(r1) - 1.f);
        *(float2*)(g.outp + (size_t)n * 100 + cc0) = make_float2(r0, r1);
    }
}

// ---------------- layer-2 gather: wave per dst node, heads=1, 256B-aligned bf16 rows ----------------
struct Gather1Args {
    const int* ro;
    const int* ss;
    const u16* hp;     // [Ns][128] bf16: 0..99 payload
    const float* as_;  // [Ns] fp32
    const float* ad;   // [Nd] fp32
    const float* bias; // [100]
    float* outp;       // [Nd,100]
};

__global__ __launch_bounds__(256) void gather1_kernel(Gather1Args ga0, Gather1Args ga1, int Nd) {
    const Gather1Args ga[2] = {ga0, ga1};
    const Gather1Args g = ga[blockIdx.y];
    int wid = (int)((blockIdx.x * blockDim.x + threadIdx.x) >> 6);
    if (wid >= Nd) return;
    const int n = __builtin_amdgcn_readfirstlane(wid);
    const int lane = threadIdx.x & 63;
    const int beg = g.ro[n], end = g.ro[n + 1];
    const bool act = (lane < 50);
    const int cc0 = act ? 2 * lane : 0;
    const float adn = g.ad[n];
    float acc0 = 0.f, acc1 = 0.f, d0 = 0.f;

    auto edge = [&](u32 va, float asq, float& po) {
        float l = asq + adn;
        l = fmaxf(l, 0.2f * l);
        const float p = __expf(l);
        acc0 = fmaf(p, b2f((u16)va), acc0);
        acc1 = fmaf(p, b2f((u16)(va >> 16)), acc1);
        po = p;
    };

    struct G1 { u32 va0, va1, va2, va3; float a0, a1, a2, a3; };
    auto load4 = [&](int off) -> G1 {
        G1 r;
        const int o = __builtin_amdgcn_readfirstlane(off);
        const int s0 = g.ss[o];
        const int s1 = g.ss[o + 1];
        const int s2 = g.ss[o + 2];
        const int s3 = g.ss[o + 3];
        r.a0 = g.as_[s0];
        r.a1 = g.as_[s1];
        r.a2 = g.as_[s2];
        r.a3 = g.as_[s3];
        r.va0 = *(const u32*)(g.hp + (size_t)s0 * 128 + cc0);
        r.va1 = *(const u32*)(g.hp + (size_t)s1 * 128 + cc0);
        r.va2 = *(const u32*)(g.hp + (size_t)s2 * 128 + cc0);
        r.va3 = *(const u32*)(g.hp + (size_t)s3 * 128 + cc0);
        return r;
    };
    auto compute4 = [&](const G1& e) {
        float pa, pb;
        edge(e.va0, e.a0, pa);
        edge(e.va1, e.a1, pb);
        d0 += pa + pb;
        edge(e.va2, e.a2, pa);
        edge(e.va3, e.a3, pb);
        d0 += pa + pb;
    };

    int i = beg;
    const int last4 = beg + ((end - beg) & ~3);
    const int ng = (last4 - beg) >> 2;
    if (ng >= 2) {  // 2-deep pipeline
        G1 cur = load4(i);
        G1 nxt = load4(i + 4);
        i += 8;
        for (; i < last4; i += 4) {
            G1 nn = load4(i);
            __builtin_amdgcn_sched_barrier(0);  // keep prefetch above compute
            compute4(cur);
            cur = nxt;
            nxt = nn;
        }
        compute4(cur);
        compute4(nxt);
    } else if (ng == 1) {
        G1 cur = load4(i);
        compute4(cur);
        i += 4;
    }
    if (i + 1 < end) {  // 2-3 remain -> pair
        const int o = __builtin_amdgcn_readfirstlane(i);
        const int s0 = g.ss[o], s1 = g.ss[o + 1];
        const float a0 = g.as_[s0], a1 = g.as_[s1];
        const u32 va0 = *(const u32*)(g.hp + (size_t)s0 * 128 + cc0);
        const u32 va1 = *(const u32*)(g.hp + (size_t)s1 * 128 + cc0);
        float pa, pb;
        edge(va0, a0, pa);
        edge(va1, a1, pb);
        d0 += pa + pb;
        i += 2;
    }
    if (i < end) {  // single
        const int o = __builtin_amdgcn_readfirstlane(i);
        const int s0 = g.ss[o];
        const float a0 = g.as_[s0];
        const u32 va0 = *(const u32*)(g.hp + (size_t)s0 * 128 + cc0);
        float pa;
        edge(va0, a0, pa);
        d0 += pa;
    }

    if (act) {
        float r0 = (end > beg) ? acc0 / d0 : 0.f;
        float r1 = (end > beg) ? acc1 / d0 : 0.f;
        r0 += g.bias[cc0];
        r1 += g.bias[cc0 + 1];
        *(float2*)(g.outp + (size_t)n * 100 + cc0) = make_float2(r0, r1);
    }
}

extern "C" void kernel_launch(void* const* d_in, const int* in_sizes, int n_in,
                              void* d_out, int out_size, void* d_ws, size_t ws_size,
                              hipStream_t stream) {
    const float* x_A   = (const float*)d_in[0];
    const float* x_B   = (const float*)d_in[1];
    const int*   ei_AB = (const int*)d_in[2];
    const int*   ei_BA = (const int*)d_in[3];
    const float* w_AB  = (const float*)d_in[4];
    const float* w_BA  = (const float*)d_in[5];
    const float* l1AB_Ws = (const float*)d_in[6];
    const float* l1AB_Wd = (const float*)d_in[7];
    const float* l1AB_as = (const float*)d_in[8];
    const float* l1AB_ad = (const float*)d_in[9];
    const float* l1AB_We = (const float*)d_in[10];
    const float* l1AB_ae = (const float*)d_in[11];
    const float* l1AB_b  = (const float*)d_in[12];
    const float* l2AB_Ws = (const float*)d_in[13];
    const float* l2AB_Wd = (const float*)d_in[14];
    const float* l2AB_as = (const float*)d_in[15];
    const float* l2AB_ad = (const float*)d_in[16];
    const float* l2AB_b  = (const float*)d_in[17];
    const float* l1BA_Ws = (const float*)d_in[18];
    const float* l1BA_Wd = (const float*)d_in[19];
    const float* l1BA_as = (const float*)d_in[20];
    const float* l1BA_ad = (const float*)d_in[21];
    const float* l1BA_We = (const float*)d_in[22];
    const float* l1BA_ae = (const float*)d_in[23];
    const float* l1BA_b  = (const float*)d_in[24];
    const float* l2BA_Ws = (const float*)d_in[25];
    const float* l2BA_Wd = (const float*)d_in[26];
    const float* l2BA_as = (const float*)d_in[27];
    const float* l2BA_ad = (const float*)d_in[28];
    const float* l2BA_b  = (const float*)d_in[29];

    const int N = NNODES, E = NEDGES;

    // ---- workspace carve (4-byte elements, 64-element aligned) ----
    size_t o = 0;
    auto alloc = [&](size_t n) { size_t r = o; o += (n + 63) & ~(size_t)63; return r; };
    size_t cntA = alloc(N), cntB = alloc(N);
    size_t roA = alloc(N + 1), roB = alloc(N + 1);
    size_t curA = alloc(N), curB = alloc(N);
    size_t ssA = alloc(E), ssB = alloc(E);
    size_t swA = alloc(E), swB = alloc(E);
    size_t ce8 = alloc(8);
    size_t part = alloc(128);
    size_t pHAB = alloc((size_t)N * 64);  // packed bf16 [N][128] as uints (256B rows)
    size_t pHBA = alloc((size_t)N * 64);
    size_t ad1B = alloc((size_t)N * 4), ad1A = alloc((size_t)N * 4);
    size_t hA1 = alloc((size_t)N * 100), hB1 = alloc((size_t)N * 100);
    size_t H2AB = alloc((size_t)N * 64);  // packed bf16 [N][128] as uints (256B rows)
    size_t H2BA = alloc((size_t)N * 64);
    size_t as2AB = alloc(N), as2BA = alloc(N);
    size_t ad2AB = alloc(N), ad2BA = alloc(N);
    (void)ws_size;

    float* wsf = (float*)d_ws;
    int*   wsi = (int*)d_ws;
    u32*   wsu = (u32*)d_ws;

    // zero edge-count histograms (cntA..cntB contiguous span)
    hipMemsetAsync(wsi + cntA, 0, sizeof(int) * (cntB + N - cntA), stream);

    ce_kernel<<<2, 128, 0, stream>>>(l1AB_We, l1AB_ae, l1BA_We, l1BA_ae, wsf + ce8);

    const int eb = (2 * E + 255) / 256;
    count_kernel<<<eb, 256, 0, stream>>>(ei_AB, ei_BA, E, wsi + cntA, wsi + cntB);
    scanA_kernel<<<dim3(SCAN_NBLK, 2), SCAN_T, 0, stream>>>(
        wsi + cntA, wsi + cntB, wsi + roA, wsi + roB, wsi + part, N);
    scanB_kernel<<<1, 128, 0, stream>>>(wsi + part, SCAN_NBLK);
    scanC_kernel<<<dim3(SCAN_NBLK, 2), SCAN_T, 0, stream>>>(
        wsi + cntA, wsi + cntB, wsi + roA, wsi + roB, wsi + curA, wsi + curB, wsi + part, N);
    fill_kernel<<<eb, 256, 0, stream>>>(ei_AB, ei_BA, w_AB, w_BA, E, wsi + curA, wsi + curB,
                                        wsi + ssA, wsi + ssB, wsf + swA, wsf + swB);

    const int gb = (N + 127) / 128;  // 391
    // layer-1 node transforms (src roles -> packed bf16 tables; dst roles -> a_dst only)
    {
        GemmArgs g0 = {x_A, l1AB_Ws, l1AB_as, (void*)(wsu + pHAB), nullptr};
        GemmArgs g1 = {x_B, l1AB_Wd, l1AB_ad, nullptr, wsf + ad1B};
        GemmArgs g2 = {x_B, l1BA_Ws, l1BA_as, (void*)(wsu + pHBA), nullptr};
        GemmArgs g3 = {x_A, l1BA_Wd, l1BA_ad, nullptr, wsf + ad1A};
        gemm_att_kernel<128, 4><<<dim3(gb, 4), 256, 0, stream>>>(g0, g1, g2, g3, N);
    }

    const int wb = (N + 3) / 4;  // wave per node, 4 waves/block
    {
        Gather4Args g0 = {wsi + roA, wsi + ssA, wsf + swA, (const u16*)(wsu + pHAB),
                          wsf + ad1B, wsf + ce8, l1AB_b, wsf + hB1};
        Gather4Args g1 = {wsi + roB, wsi + ssB, wsf + swB, (const u16*)(wsu + pHBA),
                          wsf + ad1A, wsf + ce8 + 4, l1BA_b, wsf + hA1};
        gather4_kernel<<<dim3(wb, 2), 256, 0, stream>>>(g0, g1, N);
    }

    // layer-2 node transforms (src roles -> packed bf16 H + as; dst roles -> ad only)
    {
        GemmArgs g0 = {wsf + hA1, l2AB_Ws, l2AB_as, (void*)(wsu + H2AB), wsf + as2AB};
        GemmArgs g1 = {wsf + hB1, l2AB_Wd, l2AB_ad, nullptr, wsf + ad2AB};
        GemmArgs g2 = {wsf + hB1, l2BA_Ws, l2BA_as, (void*)(wsu + H2BA), wsf + as2BA};
        GemmArgs g3 = {wsf + hA1, l2BA_Wd, l2BA_ad, nullptr, wsf + ad2BA};
        gemm_att_kernel<100, 1><<<dim3(gb, 4), 256, 0, stream>>>(g0, g1, g2, g3, N);
    }

    float* out = (float*)d_out;
    // oA = BA direction (dst in A) -> d_out[0..5M); oB = AB direction -> d_out[5M..10M)
    {
        Gather1Args g0 = {wsi + roA, wsi + ssA, (const u16*)(wsu + H2AB), wsf + as2AB,
                          wsf + ad2AB, l2AB_b, out + (size_t)N * 100};
        Gather1Args g1 = {wsi + roB, wsi + ssB, (const u16*)(wsu + H2BA), wsf + as2BA,
                          wsf + ad2BA, l2BA_b, out};
        gather1_kernel<<<dim3(wb, 2), 256, 0, stream>>>(g0, g1, N);
    }
}